// Round 1
// baseline (1266.934 us; speedup 1.0000x reference)
//
#include <hip/hip_runtime.h>

// Problem constants
// B=8, N=2048, DIN=256, DOUT=256
// Out[b,n,0:256]   = relu(0.5*(M1+M2))          M1 = G@Ne, M2 = G^T@Ne, Ne = H@W
// Out[b,n,256:512] = relu(G^T @ (M1 * inv_rs))  rs = row sums of G
// Out[b,n,512:768] = relu(G   @ (M2 * inv_cs))  cs = col sums of G

constexpr int BM = 64, BN = 64, BK = 16;
constexpr int KC = 8;  // colsum k-chunks

// ---------------- generic tiled fp32 GEMM ----------------
// C[i,j] = sum_k Alog[i,k] * (B[k,j] * scaleK[k])   (scaleK==nullptr -> 1)
// TRANSA: Alog[i,k] = Astore[k*M + i]  (Astore is [K,M] row-major)
// else  : Alog[i,k] = Astore[i*K + k]  (lda == K)
template <bool TRANSA, bool RELU>
__global__ __launch_bounds__(256) void gemm_kernel(
    const float* __restrict__ A, const float* __restrict__ Bm,
    float* __restrict__ C, const float* __restrict__ scaleK,
    int M, int Nn, int K, int ldb, int ldc,
    long sA, long sB, long sC, long sS)
{
    __shared__ float As[BK][BM + 4];
    __shared__ float Bs[BK][BN + 4];

    const int b  = blockIdx.z;
    const int i0 = blockIdx.x * BM;
    const int j0 = blockIdx.y * BN;
    A  += (long)b * sA;
    Bm += (long)b * sB;
    C  += (long)b * sC;
    const float* sk = scaleK ? scaleK + (long)b * sS : nullptr;

    const int t  = threadIdx.x;
    const int tx = t & 15;   // 0..15 -> j micro
    const int ty = t >> 4;   // 0..15 -> i micro

    float acc[4][4] = {};

    for (int k0 = 0; k0 < K; k0 += BK) {
        // ---- stage A tile: As[kk][i] = Alog[i0+i, k0+kk]
        if (TRANSA) {
            const int kk = t >> 4;           // 0..15
            const int ib = (t & 15) * 4;     // 0..60
            const float4 v = *(const float4*)(A + (long)(k0 + kk) * M + i0 + ib);
            *(float4*)&As[kk][ib] = v;
        } else {
            const int i  = t >> 2;           // 0..63
            const int kb = (t & 3) * 4;      // 0,4,8,12
            const float4 v = *(const float4*)(A + (long)(i0 + i) * K + k0 + kb);
            As[kb + 0][i] = v.x;
            As[kb + 1][i] = v.y;
            As[kb + 2][i] = v.z;
            As[kb + 3][i] = v.w;
        }
        // ---- stage B tile: Bs[kk][j] = B[k0+kk, j0+j] * scale
        {
            const int kk = t >> 4;           // 0..15
            const int jb = (t & 15) * 4;     // 0..60
            float4 v = *(const float4*)(Bm + (long)(k0 + kk) * ldb + j0 + jb);
            if (sk) {
                const float s = sk[k0 + kk];
                v.x *= s; v.y *= s; v.z *= s; v.w *= s;
            }
            *(float4*)&Bs[kk][jb] = v;
        }
        __syncthreads();

        #pragma unroll
        for (int kk = 0; kk < BK; ++kk) {
            const float4 a  = *(const float4*)&As[kk][ty * 4];
            const float4 bb = *(const float4*)&Bs[kk][tx * 4];
            const float ar[4] = {a.x, a.y, a.z, a.w};
            const float br[4] = {bb.x, bb.y, bb.z, bb.w};
            #pragma unroll
            for (int m = 0; m < 4; ++m)
                #pragma unroll
                for (int n = 0; n < 4; ++n)
                    acc[m][n] = fmaf(ar[m], br[n], acc[m][n]);
        }
        __syncthreads();
    }

    // ---- epilogue
    #pragma unroll
    for (int m = 0; m < 4; ++m) {
        float4 v = make_float4(acc[m][0], acc[m][1], acc[m][2], acc[m][3]);
        if (RELU) {
            v.x = fmaxf(v.x, 0.f); v.y = fmaxf(v.y, 0.f);
            v.z = fmaxf(v.z, 0.f); v.w = fmaxf(v.w, 0.f);
        }
        *(float4*)(C + (long)(i0 + ty * 4 + m) * ldc + j0 + tx * 4) = v;
    }
}

// ---------------- row sums -> reciprocal ----------------
__global__ __launch_bounds__(256) void rowsum_kernel(
    const float* __restrict__ G, float* __restrict__ inv_rs, int N)
{
    const long row = blockIdx.x;             // b*N + i
    const float* g = G + row * (long)N;
    float s = 0.f;
    for (int j = threadIdx.x; j < N; j += 256) s += g[j];
    #pragma unroll
    for (int off = 32; off > 0; off >>= 1) s += __shfl_down(s, off);
    __shared__ float red[4];
    if ((threadIdx.x & 63) == 0) red[threadIdx.x >> 6] = s;
    __syncthreads();
    if (threadIdx.x == 0)
        inv_rs[row] = 1.0f / (red[0] + red[1] + red[2] + red[3]);
}

// ---------------- column sums (two stage) ----------------
__global__ __launch_bounds__(256) void colsum_partial(
    const float* __restrict__ G, float* __restrict__ part, int N)
{
    const int b  = blockIdx.z;
    const int jc = blockIdx.x;
    const int kc = blockIdx.y;
    const int j  = jc * 256 + threadIdx.x;
    const float* g = G + (long)b * N * N;
    const int k0 = kc * (N / KC);
    float s = 0.f;
    for (int k = k0; k < k0 + N / KC; ++k) s += g[(long)k * N + j];
    part[((long)b * KC + kc) * N + j] = s;
}

__global__ __launch_bounds__(256) void finalize_cs(
    const float* __restrict__ part, float* __restrict__ inv_cs, int N)
{
    const int b = blockIdx.y;
    const int j = blockIdx.x * 256 + threadIdx.x;
    float s = 0.f;
    #pragma unroll
    for (int kc = 0; kc < KC; ++kc) s += part[((long)b * KC + kc) * N + j];
    inv_cs[(long)b * N + j] = 1.0f / s;
}

// ---------------- Out[:, 0:256] = relu(0.5*(M1+M2)) ----------------
__global__ __launch_bounds__(256) void out1_kernel(
    const float4* __restrict__ M1, const float4* __restrict__ M2,
    float* __restrict__ out)
{
    const long idx = (long)blockIdx.x * 256 + threadIdx.x;  // float4 index over [B*N, 64]
    const long row = idx >> 6;
    const int  j4  = (int)(idx & 63);
    const float4 a = M1[idx];
    const float4 b = M2[idx];
    float4 v;
    v.x = fmaxf(0.5f * (a.x + b.x), 0.f);
    v.y = fmaxf(0.5f * (a.y + b.y), 0.f);
    v.z = fmaxf(0.5f * (a.z + b.z), 0.f);
    v.w = fmaxf(0.5f * (a.w + b.w), 0.f);
    *(float4*)(out + row * 768 + j4 * 4) = v;
}

extern "C" void kernel_launch(void* const* d_in, const int* in_sizes, int n_in,
                              void* d_out, int out_size, void* d_ws, size_t ws_size,
                              hipStream_t stream)
{
    constexpr int B = 8, N = 2048, DIN = 256, DOUT = 256;
    const float* H = (const float*)d_in[0];
    const float* G = (const float*)d_in[1];
    const float* W = (const float*)d_in[2];
    float* out = (float*)d_out;
    float* ws  = (float*)d_ws;

    const long bn = (long)B * N;           // 16384
    float* Ne     = ws;                    // B*N*DOUT
    float* M1     = Ne + bn * DOUT;
    float* M2     = M1 + bn * DOUT;
    float* inv_rs = M2 + bn * DOUT;        // B*N
    float* inv_cs = inv_rs + bn;
    float* cspart = inv_cs + bn;           // B*KC*N

    // sums
    rowsum_kernel<<<B * N, 256, 0, stream>>>(G, inv_rs, N);
    colsum_partial<<<dim3(N / 256, KC, B), 256, 0, stream>>>(G, cspart, N);
    finalize_cs<<<dim3(N / 256, B), 256, 0, stream>>>(cspart, inv_cs, N);

    // Ne = H @ W   ([B*N, DIN] @ [DIN, DOUT])
    gemm_kernel<false, false><<<dim3(B * N / BM, DOUT / BN, 1), 256, 0, stream>>>(
        H, W, Ne, nullptr, B * N, DOUT, DIN, DOUT, DOUT, 0, 0, 0, 0);

    const dim3 gBig(N / BM, DOUT / BN, B);
    const long sG = (long)N * N, sNe = (long)N * DOUT, sOut = (long)N * 3 * DOUT;

    // M1 = G @ Ne
    gemm_kernel<false, false><<<gBig, 256, 0, stream>>>(
        G, Ne, M1, nullptr, N, DOUT, N, DOUT, DOUT, sG, sNe, sNe, 0);
    // M2 = G^T @ Ne
    gemm_kernel<true, false><<<gBig, 256, 0, stream>>>(
        G, Ne, M2, nullptr, N, DOUT, N, DOUT, DOUT, sG, sNe, sNe, 0);

    // Out[:, 0:256] = relu(0.5*(M1+M2))
    out1_kernel<<<(int)(bn * DOUT / 4 / 256), 256, 0, stream>>>(
        (const float4*)M1, (const float4*)M2, out);

    // Out[:, 256:512] = relu(G^T @ (M1 * inv_rs))
    gemm_kernel<true, true><<<gBig, 256, 0, stream>>>(
        G, M1, out + DOUT, inv_rs, N, DOUT, N, DOUT, 3 * DOUT, sG, sNe, sOut, (long)N);
    // Out[:, 512:768] = relu(G @ (M2 * inv_cs))
    gemm_kernel<false, true><<<gBig, 256, 0, stream>>>(
        G, M2, out + 2 * DOUT, inv_cs, N, DOUT, N, DOUT, 3 * DOUT, sG, sNe, sOut, (long)N);
}

// Round 2
// 570.724 us; speedup vs baseline: 2.2199x; 2.2199x over previous
//
#include <hip/hip_runtime.h>

// B=8, N=2048, DIN=256, DOUT=256
// Ne = H@W ; M1 = G@Ne ; M2 = G^T@Ne
// out[:,0:256]   = relu(0.5*(M1+M2))
// out[:,256:512] = relu(G^T @ (M1 * inv_rs))
// out[:,512:768] = relu(G   @ (M2 * inv_cs))

constexpr int KC = 8;

using frag8   = __attribute__((ext_vector_type(8))) short;  // 8 bf16
using floatx4 = __attribute__((ext_vector_type(4))) float;

__device__ inline unsigned short f2bf(float x) {
    unsigned u = __float_as_uint(x);
    u += 0x7FFF + ((u >> 16) & 1);          // RNE
    return (unsigned short)(u >> 16);
}
__device__ inline float bf2f(unsigned short h) {
    return __uint_as_float((unsigned)h << 16);
}

enum { EPI_NE = 0, EPI_M1 = 1, EPI_M2 = 2, EPI_OUT = 3 };

// C[i,j] = sum_k Alog[i,k]*Bt[j,k]   (Bt is bf16, [256][K] per batch)
// TRANSA: Alog[i,k] = A[k*lda + i] ; else Alog[i,k] = A[i*lda + k]   (A fp32)
// Tile: 128 rows x 64 cols, BK=32. 4 waves in 2x2 (wave: 64 rows x 32 cols).
template <bool TRANSA, int EPI>
__global__ __launch_bounds__(256) void mgemm(
    const float* __restrict__ A,
    const unsigned short* __restrict__ Bt,
    const unsigned short* __restrict__ CbfIn,   // EPI_M2: M1bf
    unsigned short* __restrict__ Cbf,           // EPI_M1: normal bf16 out
    unsigned short* __restrict__ CsT,           // transposed (scaled) bf16 out [256][KcT]
    float* __restrict__ outp,                   // fp32 out, stride 768, pre-col-offset
    const float* __restrict__ scale,            // EPI_M1: inv_rs ; EPI_M2: inv_cs
    int M, int K, int lda, long sA, long sB, int KcT)
{
    __shared__ unsigned short As[128][40];      // [i][k], stride 40 (80B, 16B-aligned rows)
    __shared__ unsigned short Bs[64][40];       // [n][k]

    const int t  = threadIdx.x;
    const int i0 = blockIdx.x * 128;
    const int j0 = blockIdx.y * 64;
    const int bb  = (gridDim.z > 1) ? blockIdx.z : (i0 >> 11);
    const int i0b = (gridDim.z > 1) ? i0 : (i0 & 2047);

    const float* Ab = A + (long)bb * sA;
    const unsigned short* Btb = Bt + (long)bb * sB;

    const int w  = t >> 6;
    const int wm = w >> 1;      // 0..1 -> 64-row half
    const int wn = w & 1;       // 0..1 -> 32-col half
    const int l    = t & 63;
    const int quad = l >> 4;
    const int c15  = l & 15;

    floatx4 acc[4][2] = {};

    // staging index precompute
    const int ai  = t >> 1;            // nontrans A: row 0..127
    const int ak  = (t & 1) * 16;      // k quarter {0,16}
    const int tib = (t & 31) * 4;      // trans A: i base 0..124
    const int tkg = (t >> 5) * 4;      // trans A: k base 0..28
    const int bn  = t >> 2;            // B: n 0..63
    const int bk  = (t & 3) * 8;       // B: k base {0,8,16,24}

    for (int k0 = 0; k0 < K; k0 += 32) {
        if (!TRANSA) {
            const float* ap = Ab + (long)(i0 + ai) * lda + k0 + ak;
            const float4 x0 = *(const float4*)(ap + 0);
            const float4 x1 = *(const float4*)(ap + 4);
            const float4 x2 = *(const float4*)(ap + 8);
            const float4 x3 = *(const float4*)(ap + 12);
            *(ushort4*)&As[ai][ak + 0]  = make_ushort4(f2bf(x0.x), f2bf(x0.y), f2bf(x0.z), f2bf(x0.w));
            *(ushort4*)&As[ai][ak + 4]  = make_ushort4(f2bf(x1.x), f2bf(x1.y), f2bf(x1.z), f2bf(x1.w));
            *(ushort4*)&As[ai][ak + 8]  = make_ushort4(f2bf(x2.x), f2bf(x2.y), f2bf(x2.z), f2bf(x2.w));
            *(ushort4*)&As[ai][ak + 12] = make_ushort4(f2bf(x3.x), f2bf(x3.y), f2bf(x3.z), f2bf(x3.w));
        } else {
            const float* ap = Ab + (long)(k0 + tkg) * lda + i0 + tib;
            const float4 r0 = *(const float4*)(ap);
            const float4 r1 = *(const float4*)(ap + lda);
            const float4 r2 = *(const float4*)(ap + 2 * (long)lda);
            const float4 r3 = *(const float4*)(ap + 3 * (long)lda);
            *(ushort4*)&As[tib + 0][tkg] = make_ushort4(f2bf(r0.x), f2bf(r1.x), f2bf(r2.x), f2bf(r3.x));
            *(ushort4*)&As[tib + 1][tkg] = make_ushort4(f2bf(r0.y), f2bf(r1.y), f2bf(r2.y), f2bf(r3.y));
            *(ushort4*)&As[tib + 2][tkg] = make_ushort4(f2bf(r0.z), f2bf(r1.z), f2bf(r2.z), f2bf(r3.z));
            *(ushort4*)&As[tib + 3][tkg] = make_ushort4(f2bf(r0.w), f2bf(r1.w), f2bf(r2.w), f2bf(r3.w));
        }
        {
            const unsigned short* bp = Btb + (long)(j0 + bn) * K + k0 + bk;
            *(uint4*)&Bs[bn][bk] = *(const uint4*)bp;
        }
        __syncthreads();

        frag8 af[4], bfr[2];
        #pragma unroll
        for (int mt = 0; mt < 4; ++mt)
            af[mt] = *(const frag8*)&As[wm * 64 + mt * 16 + c15][quad * 8];
        #pragma unroll
        for (int nt = 0; nt < 2; ++nt)
            bfr[nt] = *(const frag8*)&Bs[wn * 32 + nt * 16 + c15][quad * 8];
        #pragma unroll
        for (int mt = 0; mt < 4; ++mt)
            #pragma unroll
            for (int nt = 0; nt < 2; ++nt)
                acc[mt][nt] = __builtin_amdgcn_mfma_f32_16x16x32_bf16(af[mt], bfr[nt], acc[mt][nt], 0, 0, 0);
        __syncthreads();
    }

    // epilogue: C/D layout col=lane&15, row=quad*4+reg
    #pragma unroll
    for (int mt = 0; mt < 4; ++mt) {
        const int il = wm * 64 + mt * 16 + quad * 4;
        const int ib = i0b + il;                      // batch-local row base (4 consecutive rows)
        #pragma unroll
        for (int nt = 0; nt < 2; ++nt) {
            floatx4 v = acc[mt][nt];
            const int gj = j0 + wn * 32 + nt * 16 + c15;   // 0..255
            if (EPI == EPI_NE) {
                ushort4 p = make_ushort4(f2bf(v[0]), f2bf(v[1]), f2bf(v[2]), f2bf(v[3]));
                *(ushort4*)(CsT + ((long)bb * 256 + gj) * KcT + ib) = p;
            } else if (EPI == EPI_M1) {
                #pragma unroll
                for (int r = 0; r < 4; ++r)
                    Cbf[((long)bb * 2048 + ib + r) * 256 + gj] = f2bf(v[r]);
                const float4 s = *(const float4*)(scale + (long)bb * 2048 + ib);
                ushort4 p = make_ushort4(f2bf(v[0] * s.x), f2bf(v[1] * s.y),
                                         f2bf(v[2] * s.z), f2bf(v[3] * s.w));
                *(ushort4*)(CsT + ((long)bb * 256 + gj) * KcT + ib) = p;
            } else if (EPI == EPI_M2) {
                const float4 s = *(const float4*)(scale + (long)bb * 2048 + ib);
                ushort4 p = make_ushort4(f2bf(v[0] * s.x), f2bf(v[1] * s.y),
                                         f2bf(v[2] * s.z), f2bf(v[3] * s.w));
                *(ushort4*)(CsT + ((long)bb * 256 + gj) * KcT + ib) = p;
                #pragma unroll
                for (int r = 0; r < 4; ++r) {
                    const float m1 = bf2f(CbfIn[((long)bb * 2048 + ib + r) * 256 + gj]);
                    outp[((long)bb * 2048 + ib + r) * 768 + gj] = fmaxf(0.5f * (v[r] + m1), 0.f);
                }
            } else {
                #pragma unroll
                for (int r = 0; r < 4; ++r)
                    outp[((long)bb * 2048 + ib + r) * 768 + gj] = fmaxf(v[r], 0.f);
            }
        }
    }
}

// ---------------- sums ----------------
__global__ __launch_bounds__(256) void rowsum_kernel(
    const float* __restrict__ G, float* __restrict__ inv_rs, int N)
{
    const long row = blockIdx.x;
    const float* g = G + row * (long)N;
    float s = 0.f;
    for (int j = threadIdx.x; j < N; j += 256) s += g[j];
    #pragma unroll
    for (int off = 32; off > 0; off >>= 1) s += __shfl_down(s, off);
    __shared__ float red[4];
    if ((threadIdx.x & 63) == 0) red[threadIdx.x >> 6] = s;
    __syncthreads();
    if (threadIdx.x == 0)
        inv_rs[row] = 1.0f / (red[0] + red[1] + red[2] + red[3]);
}

__global__ __launch_bounds__(256) void colsum_partial(
    const float* __restrict__ G, float* __restrict__ part, int N)
{
    const int b  = blockIdx.z;
    const int kc = blockIdx.y;
    const int j  = blockIdx.x * 256 + threadIdx.x;
    const float* g = G + (long)b * N * N;
    const int k0 = kc * (N / KC);
    float s = 0.f;
    for (int k = k0; k < k0 + N / KC; ++k) s += g[(long)k * N + j];
    part[((long)b * KC + kc) * N + j] = s;
}

__global__ __launch_bounds__(256) void finalize_cs(
    const float* __restrict__ part, float* __restrict__ inv_cs, int N)
{
    const int b = blockIdx.y;
    const int j = blockIdx.x * 256 + threadIdx.x;
    float s = 0.f;
    #pragma unroll
    for (int kc = 0; kc < KC; ++kc) s += part[((long)b * KC + kc) * N + j];
    inv_cs[(long)b * N + j] = 1.0f / s;
}

// Wt[j][k] = bf16(W[k][j])
__global__ __launch_bounds__(256) void wt_kernel(
    const float* __restrict__ W, unsigned short* __restrict__ Wt)
{
    const int j = threadIdx.x, k = blockIdx.x;
    Wt[(long)j * 256 + k] = f2bf(W[(long)k * 256 + j]);
}

extern "C" void kernel_launch(void* const* d_in, const int* in_sizes, int n_in,
                              void* d_out, int out_size, void* d_ws, size_t ws_size,
                              hipStream_t stream)
{
    constexpr int B = 8, N = 2048;
    const float* H = (const float*)d_in[0];
    const float* G = (const float*)d_in[1];
    const float* W = (const float*)d_in[2];
    float* out = (float*)d_out;

    // ws carve (bf16 buffers as ushort)
    unsigned short* ws16 = (unsigned short*)d_ws;
    unsigned short* Wt    = ws16;                         // 256*256
    unsigned short* NeT   = Wt + 256 * 256;               // 8*256*2048
    unsigned short* M1bf  = NeT + (long)B * 256 * 2048;   // 8*2048*256
    unsigned short* M1sT  = M1bf + (long)B * 2048 * 256;  // 8*256*2048
    unsigned short* M2sT  = M1sT + (long)B * 256 * 2048;  // 8*256*2048
    float* fp = (float*)(M2sT + (long)B * 256 * 2048);
    float* inv_rs = fp;                                   // B*N
    float* inv_cs = inv_rs + (long)B * N;
    float* cspart = inv_cs + (long)B * N;                 // B*KC*N

    const long sG = (long)N * N;
    const long sNT = 256L * 2048;

    rowsum_kernel<<<B * N, 256, 0, stream>>>(G, inv_rs, N);
    colsum_partial<<<dim3(N / 256, KC, B), 256, 0, stream>>>(G, cspart, N);
    finalize_cs<<<dim3(N / 256, B), 256, 0, stream>>>(cspart, inv_cs, N);
    wt_kernel<<<256, 256, 0, stream>>>(W, Wt);

    // NeT = (H@W)^T per batch   [M=16384, K=256]
    mgemm<false, EPI_NE><<<dim3(128, 4, 1), 256, 0, stream>>>(
        H, Wt, nullptr, nullptr, NeT, nullptr, nullptr, B * N, 256, 256, 0, 0, 2048);
    // M1 = G@Ne -> M1bf + M1sT(scaled by inv_rs)
    mgemm<false, EPI_M1><<<dim3(16, 4, 8), 256, 0, stream>>>(
        G, NeT, nullptr, M1bf, M1sT, nullptr, inv_rs, N, N, N, sG, sNT, 2048);
    // M2 = G^T@Ne -> M2sT(scaled by inv_cs) + fused out1=relu(0.5*(M1+M2))
    mgemm<true, EPI_M2><<<dim3(16, 4, 8), 256, 0, stream>>>(
        G, NeT, M1bf, nullptr, M2sT, out, inv_cs, N, N, N, sG, sNT, 2048);
    // out2 = relu(G^T @ M1s)
    mgemm<true, EPI_OUT><<<dim3(16, 4, 8), 256, 0, stream>>>(
        G, M1sT, nullptr, nullptr, nullptr, out + 256, nullptr, N, N, N, sG, sNT, 0);
    // out3 = relu(G @ M2s)
    mgemm<false, EPI_OUT><<<dim3(16, 4, 8), 256, 0, stream>>>(
        G, M2sT, nullptr, nullptr, nullptr, out + 512, nullptr, N, N, N, sG, sNT, 0);
}

// Round 4
// 509.377 us; speedup vs baseline: 2.4872x; 1.1204x over previous
//
#include <hip/hip_runtime.h>
#include <hip/hip_bf16.h>

// B=8, N=2048, DIN=256, DOUT=256
// Ne = H@W ; M1 = G@Ne ; M2 = G^T@Ne
// out[:,0:256]   = relu(0.5*(M1+M2))
// out[:,256:512] = relu(G^T @ (M1 * inv_rs))
// out[:,512:768] = relu(G   @ (M2 * inv_cs))

constexpr int NN = 2048;
constexpr int KC = 8;
constexpr long GSTR = (long)NN * NN;

using frag8   = __attribute__((ext_vector_type(8))) short;   // 8 bf16
using floatx4 = __attribute__((ext_vector_type(4))) float;
using ush8    = __attribute__((ext_vector_type(8))) unsigned short;

__device__ inline unsigned short f2bf(float x) {
    unsigned u = __float_as_uint(x);
    u += 0x7FFF + ((u >> 16) & 1);   // RNE
    return (unsigned short)(u >> 16);
}
__device__ inline float bf2f(unsigned short h) {
    return __uint_as_float((unsigned)h << 16);
}
__device__ inline ushort2 pk2(float a, float b) {
    union { __hip_bfloat162 h; ushort2 u; } cv;
    cv.h = __float22bfloat162_rn(float2{a, b});
    return cv.u;
}
__device__ inline void gload_lds16(const void* g, void* l) {
    __builtin_amdgcn_global_load_lds(
        (const __attribute__((address_space(1))) void*)g,
        (__attribute__((address_space(3))) void*)l, 16, 0, 0);
}

enum { EPI_NE = 0, EPI_M1 = 1, EPI_P2 = 2, EPI_O3 = 3 };
enum { A_F32ROW = 0, A_F32TRANS = 1, A_DMA = 2 };

// C[i,j] = sum_k Alog[i,k] * Bt[j,k]; Bt bf16 [n][K] staged via global_load_lds.
// A: F32ROW   = fp32 row-major [i][k] (lda), in-loop pk-cvt, LDS stride 72
//    F32TRANS = fp32 [k][i] (lda = row stride over k), reg-transpose, stride 72
//    DMA      = bf16 row-major [i][K], global_load_lds, LDS stride 64
// Tile 64x64, BK=64, 4 waves in 2x2 (wave = 32x32 = 2x2 MFMA 16x16x32).
template <int EPI, int AMODE>
__global__ __launch_bounds__(256) void mgemm(
    const void* __restrict__ Aptr,
    const unsigned short* __restrict__ B0,
    const unsigned short* __restrict__ B1,     // P2: M1sT (for j0>=256)
    const unsigned short* __restrict__ M1in,   // P2: M1bf
    unsigned short* __restrict__ M1bfp,        // M1 out (row-major bf16)
    unsigned short* __restrict__ CsT,          // transposed bf16 out [256][2048]
    float* __restrict__ outp,                  // fp32 out base (stride 768)
    const float* __restrict__ scale,           // M1: inv_rs ; P2: inv_cs
    int K, int lda, long strideA, long sB)
{
    constexpr int ASTR = (AMODE == A_DMA) ? 64 : 72;
    __shared__ __align__(16) unsigned short As[64 * 72];
    __shared__ __align__(16) unsigned short Bs[64 * 64];

    const int t   = threadIdx.x;
    const int i0b = blockIdx.x * 64;     // batch-local row tile
    const int j0  = blockIdx.y * 64;
    const int bb  = blockIdx.z;

    const unsigned short* Btb =
        ((EPI == EPI_P2 && j0 >= 256) ? B1 + (long)(j0 - 256) * K
                                      : B0 + (long)j0 * K) + (long)bb * sB;

    const int w = t >> 6, l = t & 63;
    const int wm = w >> 1, wn = w & 1;
    const int quad = l >> 4, c15 = l & 15;

    // staging index precompute
    const int ar  = t >> 2;            // F32ROW: row 0..63
    const int akc = (t & 3) * 16;      // F32ROW: k base
    const int tc  = (t & 15) * 4;      // F32TRANS: i base
    const int trg = (t >> 4) * 4;      // F32TRANS: k base

    floatx4 acc[2][2] = {};

    for (int k0 = 0; k0 < K; k0 += 64) {
        // ---- stage A
        if constexpr (AMODE == A_DMA) {
            const unsigned short* Au = (const unsigned short*)Aptr + (long)bb * strideA;
            #pragma unroll
            for (int q = 0; q < 2; ++q) {
                const int rt = w * 16 + q * 8;
                gload_lds16(Au + (long)(i0b + rt + (l >> 3)) * lda + k0 + (l & 7) * 8,
                            &As[rt * 64]);
            }
        } else if constexpr (AMODE == A_F32ROW) {
            const float* Af = (const float*)Aptr + (long)bb * strideA;
            const float* ap = Af + (long)(i0b + ar) * lda + k0 + akc;
            const float4 x0 = *(const float4*)(ap + 0);
            const float4 x1 = *(const float4*)(ap + 4);
            const float4 x2 = *(const float4*)(ap + 8);
            const float4 x3 = *(const float4*)(ap + 12);
            union { ush8 v; ushort2 u2[4]; } p0, p1;
            p0.u2[0] = pk2(x0.x, x0.y); p0.u2[1] = pk2(x0.z, x0.w);
            p0.u2[2] = pk2(x1.x, x1.y); p0.u2[3] = pk2(x1.z, x1.w);
            p1.u2[0] = pk2(x2.x, x2.y); p1.u2[1] = pk2(x2.z, x2.w);
            p1.u2[2] = pk2(x3.x, x3.y); p1.u2[3] = pk2(x3.z, x3.w);
            *(ush8*)&As[ar * 72 + akc]     = p0.v;
            *(ush8*)&As[ar * 72 + akc + 8] = p1.v;
        } else {  // A_F32TRANS: A stored [k][i]
            const float* Af = (const float*)Aptr + (long)bb * strideA;
            const float* ap = Af + (long)(k0 + trg) * lda + i0b + tc;
            const float4 v0 = *(const float4*)(ap);
            const float4 v1 = *(const float4*)(ap + lda);
            const float4 v2 = *(const float4*)(ap + 2 * (long)lda);
            const float4 v3 = *(const float4*)(ap + 3 * (long)lda);
            const float r0[4] = {v0.x, v0.y, v0.z, v0.w};
            const float r1[4] = {v1.x, v1.y, v1.z, v1.w};
            const float r2[4] = {v2.x, v2.y, v2.z, v2.w};
            const float r3[4] = {v3.x, v3.y, v3.z, v3.w};
            #pragma unroll
            for (int q = 0; q < 4; ++q) {
                union { ushort4 v; ushort2 u2[2]; } o;
                o.u2[0] = pk2(r0[q], r1[q]);
                o.u2[1] = pk2(r2[q], r3[q]);
                *(ushort4*)&As[(tc + q) * 72 + trg] = o.v;
            }
        }
        // ---- stage B (always DMA)
        #pragma unroll
        for (int q = 0; q < 2; ++q) {
            const int rt = w * 16 + q * 8;
            gload_lds16(Btb + (long)(rt + (l >> 3)) * K + k0 + (l & 7) * 8,
                        &Bs[rt * 64]);
        }
        __syncthreads();

        #pragma unroll
        for (int ks = 0; ks < 2; ++ks) {
            frag8 af[2], bfv[2];
            #pragma unroll
            for (int mt = 0; mt < 2; ++mt)
                af[mt] = *(const frag8*)&As[(wm * 32 + mt * 16 + c15) * ASTR + ks * 32 + quad * 8];
            #pragma unroll
            for (int nt = 0; nt < 2; ++nt)
                bfv[nt] = *(const frag8*)&Bs[(wn * 32 + nt * 16 + c15) * 64 + ks * 32 + quad * 8];
            #pragma unroll
            for (int mt = 0; mt < 2; ++mt)
                #pragma unroll
                for (int nt = 0; nt < 2; ++nt)
                    acc[mt][nt] = __builtin_amdgcn_mfma_f32_16x16x32_bf16(
                        af[mt], bfv[nt], acc[mt][nt], 0, 0, 0);
        }
        __syncthreads();
    }

    // ---- epilogue: C/D layout col=lane&15, row=quad*4+reg
    const long rowb = (long)bb * NN;
    #pragma unroll
    for (int mt = 0; mt < 2; ++mt) {
        const int il = wm * 32 + mt * 16 + quad * 4;
        const int ib = i0b + il;
        float4 s4 = make_float4(1.f, 1.f, 1.f, 1.f);
        if constexpr (EPI == EPI_M1) s4 = *(const float4*)(scale + rowb + ib);
        if constexpr (EPI == EPI_P2) {
            if (j0 < 256) s4 = *(const float4*)(scale + rowb + ib);
        }
        #pragma unroll
        for (int nt = 0; nt < 2; ++nt) {
            floatx4 v = acc[mt][nt];
            const int gj = j0 + wn * 32 + nt * 16 + c15;
            if constexpr (EPI == EPI_NE) {
                union { ushort4 v; ushort2 u2[2]; } p;
                p.u2[0] = pk2(v[0], v[1]); p.u2[1] = pk2(v[2], v[3]);
                *(ushort4*)(CsT + ((long)bb * 256 + gj) * 2048 + ib) = p.v;
            } else if constexpr (EPI == EPI_M1) {
                #pragma unroll
                for (int r = 0; r < 4; ++r)
                    M1bfp[(rowb + ib + r) * 256 + gj] = f2bf(v[r]);
                union { ushort4 v; ushort2 u2[2]; } p;
                p.u2[0] = pk2(v[0] * s4.x, v[1] * s4.y);
                p.u2[1] = pk2(v[2] * s4.z, v[3] * s4.w);
                *(ushort4*)(CsT + ((long)bb * 256 + gj) * 2048 + ib) = p.v;
            } else if constexpr (EPI == EPI_P2) {
                if (j0 < 256) {
                    union { ushort4 v; ushort2 u2[2]; } p;
                    p.u2[0] = pk2(v[0] * s4.x, v[1] * s4.y);
                    p.u2[1] = pk2(v[2] * s4.z, v[3] * s4.w);
                    *(ushort4*)(CsT + ((long)bb * 256 + gj) * 2048 + ib) = p.v;
                    #pragma unroll
                    for (int r = 0; r < 4; ++r) {
                        const float m1 = bf2f(M1in[(rowb + ib + r) * 256 + gj]);
                        outp[(rowb + ib + r) * 768 + gj] = fmaxf(0.5f * (v[r] + m1), 0.f);
                    }
                } else {
                    #pragma unroll
                    for (int r = 0; r < 4; ++r)
                        outp[(rowb + ib + r) * 768 + gj] = fmaxf(v[r], 0.f);
                }
            } else {  // EPI_O3
                #pragma unroll
                for (int r = 0; r < 4; ++r)
                    outp[(rowb + ib + r) * 768 + 512 + gj] = fmaxf(v[r], 0.f);
            }
        }
    }
}

// ---- G (fp32) -> GT (bf16 transposed [b][col][row]) ---- (big-ws tier only)
__global__ __launch_bounds__(256) void cvtT(
    const float* __restrict__ G, unsigned short* __restrict__ GT)
{
    __shared__ float Tf[64 * 65];
    const int b = blockIdx.z;
    const int j0 = blockIdx.x * 64, i0 = blockIdx.y * 64;
    const int t = threadIdx.x;
    const int r = t >> 2, cb = (t & 3) * 16;
    const float* src = G + (long)b * GSTR + (long)(i0 + r) * NN + j0 + cb;
    #pragma unroll
    for (int q = 0; q < 4; ++q) {
        const float4 v = *(const float4*)(src + q * 4);
        Tf[r * 65 + cb + q * 4 + 0] = v.x;
        Tf[r * 65 + cb + q * 4 + 1] = v.y;
        Tf[r * 65 + cb + q * 4 + 2] = v.z;
        Tf[r * 65 + cb + q * 4 + 3] = v.w;
    }
    __syncthreads();
    const int co = t >> 2, rb = (t & 3) * 16;
    unsigned short* dst = GT + (long)b * GSTR + (long)(j0 + co) * NN + i0 + rb;
    #pragma unroll
    for (int q = 0; q < 4; ++q) {
        union { ushort4 v; ushort2 u2[2]; } p;
        p.u2[0] = pk2(Tf[(rb + q * 4 + 0) * 65 + co], Tf[(rb + q * 4 + 1) * 65 + co]);
        p.u2[1] = pk2(Tf[(rb + q * 4 + 2) * 65 + co], Tf[(rb + q * 4 + 3) * 65 + co]);
        *(ushort4*)(dst + q * 4) = p.v;
    }
}

// ---------------- sums (R1/R2-proven) ----------------
__global__ __launch_bounds__(256) void rowsum_kernel(
    const float* __restrict__ G, float* __restrict__ inv_rs, int N)
{
    const long row = blockIdx.x;
    const float* g = G + row * (long)N;
    float s = 0.f;
    for (int j = threadIdx.x; j < N; j += 256) s += g[j];
    #pragma unroll
    for (int off = 32; off > 0; off >>= 1) s += __shfl_down(s, off);
    __shared__ float red[4];
    if ((threadIdx.x & 63) == 0) red[threadIdx.x >> 6] = s;
    __syncthreads();
    if (threadIdx.x == 0)
        inv_rs[row] = 1.0f / (red[0] + red[1] + red[2] + red[3]);
}

__global__ __launch_bounds__(256) void colsum_partial(
    const float* __restrict__ G, float* __restrict__ part, int N)
{
    const int b  = blockIdx.z;
    const int kc = blockIdx.y;
    const int j  = blockIdx.x * 256 + threadIdx.x;
    const float* g = G + (long)b * N * N;
    const int k0 = kc * (N / KC);
    float s = 0.f;
    for (int k = k0; k < k0 + N / KC; ++k) s += g[(long)k * N + j];
    part[((long)b * KC + kc) * N + j] = s;
}

__global__ __launch_bounds__(256) void finalize_cs(
    const float* __restrict__ part, float* __restrict__ inv_cs, int N)
{
    const int b = blockIdx.y;
    const int j = blockIdx.x * 256 + threadIdx.x;
    float s = 0.f;
    #pragma unroll
    for (int kc = 0; kc < KC; ++kc) s += part[((long)b * KC + kc) * N + j];
    inv_cs[(long)b * N + j] = 1.0f / s;
}

// Wt[j][k] = bf16(W[k][j])
__global__ __launch_bounds__(256) void wt_kernel(
    const float* __restrict__ W, unsigned short* __restrict__ Wt)
{
    const int j = threadIdx.x, k = blockIdx.x;
    Wt[(long)j * 256 + k] = f2bf(W[(long)k * 256 + j]);
}

extern "C" void kernel_launch(void* const* d_in, const int* in_sizes, int n_in,
                              void* d_out, int out_size, void* d_ws, size_t ws_size,
                              hipStream_t stream)
{
    constexpr int B = 8;
    const float* H = (const float*)d_in[0];
    const float* G = (const float*)d_in[1];
    const float* W = (const float*)d_in[2];
    float* out = (float*)d_out;

    unsigned short* ws16 = (unsigned short*)d_ws;
    unsigned short* Wt   = ws16;                  // 65536
    unsigned short* NeT  = Wt + 65536;            // 4194304
    unsigned short* M1bf = NeT + 4194304;
    unsigned short* M1sT = M1bf + 4194304;
    unsigned short* M2sT = M1sT + 4194304;
    float* inv_rs = (float*)(M2sT + 4194304);     // 16384
    float* inv_cs = inv_rs + 16384;
    float* cspart = inv_cs + 16384;               // 131072
    unsigned short* GT = (unsigned short*)(cspart + 131072);  // 33554432 (T2 only)

    const bool big = ws_size >= (size_t)101449728;  // T1 needs only 34.3 MB

    rowsum_kernel<<<B * NN, 256, 0, stream>>>(G, inv_rs, NN);
    colsum_partial<<<dim3(NN / 256, KC, B), 256, 0, stream>>>(G, cspart, NN);
    finalize_cs<<<dim3(NN / 256, B), 256, 0, stream>>>(cspart, inv_cs, NN);
    wt_kernel<<<256, 256, 0, stream>>>(W, Wt);
    if (big) cvtT<<<dim3(32, 32, 8), 256, 0, stream>>>(G, GT);

    const long sNT = 256L * NN;
    // NeT = (H@W)^T : A=H fp32 [b][2048][256]
    mgemm<EPI_NE, A_F32ROW><<<dim3(32, 4, 8), 256, 0, stream>>>(
        H, Wt, nullptr, nullptr, nullptr, NeT, nullptr, nullptr,
        256, 256, 2048L * 256, 0);
    // M1 = G@Ne -> M1bf + M1sT (scaled inv_rs)
    mgemm<EPI_M1, A_F32ROW><<<dim3(32, 4, 8), 256, 0, stream>>>(
        G, NeT, nullptr, nullptr, M1bf, M1sT, nullptr, inv_rs,
        2048, 2048, GSTR, sNT);
    // P2: A=G^T, B=[NeT ; M1sT] -> M2sT (scaled inv_cs) + out1 + out2
    if (big)
        mgemm<EPI_P2, A_DMA><<<dim3(32, 8, 8), 256, 0, stream>>>(
            GT, NeT, M1sT, M1bf, nullptr, M2sT, out, inv_cs,
            2048, 2048, GSTR, sNT);
    else
        mgemm<EPI_P2, A_F32TRANS><<<dim3(32, 8, 8), 256, 0, stream>>>(
            G, NeT, M1sT, M1bf, nullptr, M2sT, out, inv_cs,
            2048, 2048, GSTR, sNT);
    // out3 = relu(G @ M2s)
    mgemm<EPI_O3, A_F32ROW><<<dim3(32, 4, 8), 256, 0, stream>>>(
        G, M2sT, nullptr, nullptr, nullptr, nullptr, out, nullptr,
        2048, 2048, GSTR, sNT);
}

// Round 5
// 495.678 us; speedup vs baseline: 2.5560x; 1.0276x over previous
//
#include <hip/hip_runtime.h>
#include <hip/hip_bf16.h>

// B=8, N=2048, DIN=256, DOUT=256
// Ne = H@W ; M1 = G@Ne ; M2 = G^T@Ne
// out[:,0:256]   = relu(0.5*(M1+M2))
// out[:,256:512] = relu(G^T @ (M1 * inv_rs))
// out[:,512:768] = relu(G   @ (M2 * inv_cs))

constexpr int NN = 2048;
constexpr int KC = 8;
constexpr long GSTR = (long)NN * NN;

using frag8   = __attribute__((ext_vector_type(8))) short;   // 8 bf16
using floatx4 = __attribute__((ext_vector_type(4))) float;
using ush8    = __attribute__((ext_vector_type(8))) unsigned short;

__device__ inline unsigned short f2bf(float x) {
    unsigned u = __float_as_uint(x);
    u += 0x7FFF + ((u >> 16) & 1);   // RNE
    return (unsigned short)(u >> 16);
}
__device__ inline float bf2f(unsigned short h) {
    return __uint_as_float((unsigned)h << 16);
}
__device__ inline ushort2 pk2(float a, float b) {
    union { __hip_bfloat162 h; ushort2 u; } cv;
    cv.h = __float22bfloat162_rn(float2{a, b});
    return cv.u;
}
__device__ inline void gload_lds16(const void* g, void* l) {
    __builtin_amdgcn_global_load_lds(
        (const __attribute__((address_space(1))) void*)g,
        (__attribute__((address_space(3))) void*)l, 16, 0, 0);
}

enum { EPI_NE = 0, EPI_M1 = 1, EPI_P2 = 2, EPI_O3 = 3 };
enum { A_F32ROW = 0, A_F32TRANS = 1, A_DMA = 2 };

// C[i,j] = sum_k Alog[i,k] * Bt[j,k]; Bt bf16 [n][K] staged via global_load_lds.
// LDS layout (both As/Bs): row stride 64 shorts; 16B chunk c of row r lives at
// slot c ^ (r&7)  -> fragment ds_read_b128 is 2-way (free), staging coalesced.
// Tile 64x64, BK=64, 4 waves in 2x2 (wave = 32x32 = 2x2 MFMA 16x16x32).
template <int EPI, int AMODE>
__global__ __launch_bounds__(256) void mgemm(
    const void* __restrict__ Aptr,
    const unsigned short* __restrict__ B0,
    const unsigned short* __restrict__ B1,     // P2: M1sT (for j0>=256)
    const unsigned short* __restrict__ M1in,   // P2: M1bf
    unsigned short* __restrict__ M1bfp,        // M1 out (row-major bf16)
    unsigned short* __restrict__ CsT,          // transposed bf16 out [256][2048]
    float* __restrict__ outp,                  // fp32 out base (stride 768)
    const float* __restrict__ scale,           // M1: inv_rs ; P2: inv_cs
    int K, int lda, long strideA, long sB)
{
    __shared__ __align__(16) unsigned short As[64 * 64];
    __shared__ __align__(16) unsigned short Bs[64 * 64];

    const int t   = threadIdx.x;
    const int i0b = blockIdx.x * 64;     // batch-local row tile
    const int j0  = blockIdx.y * 64;
    const int bb  = blockIdx.z;

    const unsigned short* Btb =
        ((EPI == EPI_P2 && j0 >= 256) ? B1 + (long)(j0 - 256) * K
                                      : B0 + (long)j0 * K) + (long)bb * sB;

    const int w = t >> 6, l = t & 63;
    const int wm = w >> 1, wn = w & 1;
    const int quad = l >> 4, c15 = l & 15;

    // staging index precompute
    const int lr  = l >> 3, ls = l & 7;  // DMA: row-in-8, slot
    const int ar  = t >> 2;              // F32ROW: row 0..63
    const int ac0 = (t & 3) * 2;         // F32ROW: chunk base {0,2,4,6}
    const int tc  = (t & 15) * 4;        // F32TRANS: i base
    const int thc = t >> 4;              // F32TRANS: half-chunk 0..15
    const int tch = thc >> 1, th = thc & 1;

    floatx4 acc[2][2] = {};

    for (int k0 = 0; k0 < K; k0 += 64) {
        // ---- stage A
        if constexpr (AMODE == A_DMA) {
            const unsigned short* Au = (const unsigned short*)Aptr + (long)bb * strideA;
            #pragma unroll
            for (int q = 0; q < 2; ++q) {
                const int rt = w * 16 + q * 8;
                gload_lds16(Au + (long)(i0b + rt + lr) * lda + k0 + ((ls ^ lr) << 3),
                            &As[rt * 64]);
            }
        } else if constexpr (AMODE == A_F32ROW) {
            const float* Af = (const float*)Aptr + (long)bb * strideA;
            const float* ap = Af + (long)(i0b + ar) * lda + k0 + ac0 * 8;
            const float4 x0 = *(const float4*)(ap + 0);
            const float4 x1 = *(const float4*)(ap + 4);
            const float4 x2 = *(const float4*)(ap + 8);
            const float4 x3 = *(const float4*)(ap + 12);
            union { ush8 v; ushort2 u2[4]; } p0, p1;
            p0.u2[0] = pk2(x0.x, x0.y); p0.u2[1] = pk2(x0.z, x0.w);
            p0.u2[2] = pk2(x1.x, x1.y); p0.u2[3] = pk2(x1.z, x1.w);
            p1.u2[0] = pk2(x2.x, x2.y); p1.u2[1] = pk2(x2.z, x2.w);
            p1.u2[2] = pk2(x3.x, x3.y); p1.u2[3] = pk2(x3.z, x3.w);
            const int sw = ar & 7;
            *(ush8*)&As[ar * 64 + ((ac0 ^ sw) << 3)]       = p0.v;
            *(ush8*)&As[ar * 64 + (((ac0 + 1) ^ sw) << 3)] = p1.v;
        } else {  // A_F32TRANS: A stored [k][i]
            const float* Af = (const float*)Aptr + (long)bb * strideA;
            const float* ap = Af + (long)(k0 + thc * 4) * lda + i0b + tc;
            const float4 v0 = *(const float4*)(ap);
            const float4 v1 = *(const float4*)(ap + lda);
            const float4 v2 = *(const float4*)(ap + 2 * (long)lda);
            const float4 v3 = *(const float4*)(ap + 3 * (long)lda);
            const float r0[4] = {v0.x, v0.y, v0.z, v0.w};
            const float r1[4] = {v1.x, v1.y, v1.z, v1.w};
            const float r2[4] = {v2.x, v2.y, v2.z, v2.w};
            const float r3[4] = {v3.x, v3.y, v3.z, v3.w};
            #pragma unroll
            for (int q = 0; q < 4; ++q) {
                union { ushort4 v; ushort2 u2[2]; } o;
                o.u2[0] = pk2(r0[q], r1[q]);
                o.u2[1] = pk2(r2[q], r3[q]);
                const int row = tc + q;
                *(ushort4*)&As[row * 64 + ((tch ^ (row & 7)) << 3) + th * 4] = o.v;
            }
        }
        // ---- stage B (always DMA)
        #pragma unroll
        for (int q = 0; q < 2; ++q) {
            const int rt = w * 16 + q * 8;
            gload_lds16(Btb + (long)(rt + lr) * K + k0 + ((ls ^ lr) << 3),
                        &Bs[rt * 64]);
        }
        __syncthreads();

        #pragma unroll
        for (int ks = 0; ks < 2; ++ks) {
            frag8 af[2], bfv[2];
            const int swr = c15 & 7;
            #pragma unroll
            for (int mt = 0; mt < 2; ++mt)
                af[mt] = *(const frag8*)&As[(wm * 32 + mt * 16 + c15) * 64
                                            + (((ks * 4 + quad) ^ swr) << 3)];
            #pragma unroll
            for (int nt = 0; nt < 2; ++nt)
                bfv[nt] = *(const frag8*)&Bs[(wn * 32 + nt * 16 + c15) * 64
                                             + (((ks * 4 + quad) ^ swr) << 3)];
            #pragma unroll
            for (int mt = 0; mt < 2; ++mt)
                #pragma unroll
                for (int nt = 0; nt < 2; ++nt)
                    acc[mt][nt] = __builtin_amdgcn_mfma_f32_16x16x32_bf16(
                        af[mt], bfv[nt], acc[mt][nt], 0, 0, 0);
        }
        __syncthreads();
    }

    // ---- epilogue: C/D layout col=lane&15, row=quad*4+reg
    const long rowb = (long)bb * NN;
    #pragma unroll
    for (int mt = 0; mt < 2; ++mt) {
        const int il = wm * 32 + mt * 16 + quad * 4;
        const int ib = i0b + il;
        float4 s4 = make_float4(1.f, 1.f, 1.f, 1.f);
        if constexpr (EPI == EPI_M1) s4 = *(const float4*)(scale + rowb + ib);
        if constexpr (EPI == EPI_P2) {
            if (j0 < 256) s4 = *(const float4*)(scale + rowb + ib);
        }
        #pragma unroll
        for (int nt = 0; nt < 2; ++nt) {
            floatx4 v = acc[mt][nt];
            const int gj = j0 + wn * 32 + nt * 16 + c15;
            if constexpr (EPI == EPI_NE) {
                union { ushort4 v; ushort2 u2[2]; } p;
                p.u2[0] = pk2(v[0], v[1]); p.u2[1] = pk2(v[2], v[3]);
                *(ushort4*)(CsT + ((long)bb * 256 + gj) * 2048 + ib) = p.v;
            } else if constexpr (EPI == EPI_M1) {
                #pragma unroll
                for (int r = 0; r < 4; ++r)
                    M1bfp[(rowb + ib + r) * 256 + gj] = f2bf(v[r]);
                union { ushort4 v; ushort2 u2[2]; } p;
                p.u2[0] = pk2(v[0] * s4.x, v[1] * s4.y);
                p.u2[1] = pk2(v[2] * s4.z, v[3] * s4.w);
                *(ushort4*)(CsT + ((long)bb * 256 + gj) * 2048 + ib) = p.v;
            } else if constexpr (EPI == EPI_P2) {
                if (j0 < 256) {
                    union { ushort4 v; ushort2 u2[2]; } p;
                    p.u2[0] = pk2(v[0] * s4.x, v[1] * s4.y);
                    p.u2[1] = pk2(v[2] * s4.z, v[3] * s4.w);
                    *(ushort4*)(CsT + ((long)bb * 256 + gj) * 2048 + ib) = p.v;
                    #pragma unroll
                    for (int r = 0; r < 4; ++r) {
                        const float m1 = bf2f(M1in[(rowb + ib + r) * 256 + gj]);
                        outp[(rowb + ib + r) * 768 + gj] = fmaxf(0.5f * (v[r] + m1), 0.f);
                    }
                } else {
                    #pragma unroll
                    for (int r = 0; r < 4; ++r)
                        outp[(rowb + ib + r) * 768 + gj] = fmaxf(v[r], 0.f);
                }
            } else {  // EPI_O3
                #pragma unroll
                for (int r = 0; r < 4; ++r)
                    outp[(rowb + ib + r) * 768 + 512 + gj] = fmaxf(v[r], 0.f);
            }
        }
    }
}

// ---- G (fp32) -> GT (bf16 transposed [b][col][row]) ---- (big-ws tier only)
__global__ __launch_bounds__(256) void cvtT(
    const float* __restrict__ G, unsigned short* __restrict__ GT)
{
    __shared__ float Tf[64 * 65];
    const int b = blockIdx.z;
    const int j0 = blockIdx.x * 64, i0 = blockIdx.y * 64;
    const int t = threadIdx.x;
    const int r = t >> 2, cb = (t & 3) * 16;
    const float* src = G + (long)b * GSTR + (long)(i0 + r) * NN + j0 + cb;
    #pragma unroll
    for (int q = 0; q < 4; ++q) {
        const float4 v = *(const float4*)(src + q * 4);
        Tf[r * 65 + cb + q * 4 + 0] = v.x;
        Tf[r * 65 + cb + q * 4 + 1] = v.y;
        Tf[r * 65 + cb + q * 4 + 2] = v.z;
        Tf[r * 65 + cb + q * 4 + 3] = v.w;
    }
    __syncthreads();
    const int co = t >> 2, rb = (t & 3) * 16;
    unsigned short* dst = GT + (long)b * GSTR + (long)(j0 + co) * NN + i0 + rb;
    #pragma unroll
    for (int q = 0; q < 4; ++q) {
        union { ushort4 v; ushort2 u2[2]; } p;
        p.u2[0] = pk2(Tf[(rb + q * 4 + 0) * 65 + co], Tf[(rb + q * 4 + 1) * 65 + co]);
        p.u2[1] = pk2(Tf[(rb + q * 4 + 2) * 65 + co], Tf[(rb + q * 4 + 3) * 65 + co]);
        *(ushort4*)(dst + q * 4) = p.v;
    }
}

// ---------------- sums (R1/R2-proven) ----------------
__global__ __launch_bounds__(256) void rowsum_kernel(
    const float* __restrict__ G, float* __restrict__ inv_rs, int N)
{
    const long row = blockIdx.x;
    const float* g = G + row * (long)N;
    float s = 0.f;
    for (int j = threadIdx.x; j < N; j += 256) s += g[j];
    #pragma unroll
    for (int off = 32; off > 0; off >>= 1) s += __shfl_down(s, off);
    __shared__ float red[4];
    if ((threadIdx.x & 63) == 0) red[threadIdx.x >> 6] = s;
    __syncthreads();
    if (threadIdx.x == 0)
        inv_rs[row] = 1.0f / (red[0] + red[1] + red[2] + red[3]);
}

__global__ __launch_bounds__(256) void colsum_partial(
    const float* __restrict__ G, float* __restrict__ part, int N)
{
    const int b  = blockIdx.z;
    const int kc = blockIdx.y;
    const int j  = blockIdx.x * 256 + threadIdx.x;
    const float* g = G + (long)b * N * N;
    const int k0 = kc * (N / KC);
    float s = 0.f;
    for (int k = k0; k < k0 + N / KC; ++k) s += g[(long)k * N + j];
    part[((long)b * KC + kc) * N + j] = s;
}

__global__ __launch_bounds__(256) void finalize_cs(
    const float* __restrict__ part, float* __restrict__ inv_cs, int N)
{
    const int b = blockIdx.y;
    const int j = blockIdx.x * 256 + threadIdx.x;
    float s = 0.f;
    #pragma unroll
    for (int kc = 0; kc < KC; ++kc) s += part[((long)b * KC + kc) * N + j];
    inv_cs[(long)b * N + j] = 1.0f / s;
}

// Wt[j][k] = bf16(W[k][j])
__global__ __launch_bounds__(256) void wt_kernel(
    const float* __restrict__ W, unsigned short* __restrict__ Wt)
{
    const int j = threadIdx.x, k = blockIdx.x;
    Wt[(long)j * 256 + k] = f2bf(W[(long)k * 256 + j]);
}

extern "C" void kernel_launch(void* const* d_in, const int* in_sizes, int n_in,
                              void* d_out, int out_size, void* d_ws, size_t ws_size,
                              hipStream_t stream)
{
    constexpr int B = 8;
    const float* H = (const float*)d_in[0];
    const float* G = (const float*)d_in[1];
    const float* W = (const float*)d_in[2];
    float* out = (float*)d_out;

    unsigned short* ws16 = (unsigned short*)d_ws;
    unsigned short* Wt   = ws16;                  // 65536
    unsigned short* NeT  = Wt + 65536;            // 4194304
    unsigned short* M1bf = NeT + 4194304;
    unsigned short* M1sT = M1bf + 4194304;
    unsigned short* M2sT = M1sT + 4194304;
    float* inv_rs = (float*)(M2sT + 4194304);     // 16384
    float* inv_cs = inv_rs + 16384;
    float* cspart = inv_cs + 16384;               // 131072
    unsigned short* GT = (unsigned short*)(cspart + 131072);  // 33554432 (T2 only)

    const bool big = ws_size >= (size_t)101449728;  // T1 needs only 34.3 MB

    rowsum_kernel<<<B * NN, 256, 0, stream>>>(G, inv_rs, NN);
    colsum_partial<<<dim3(NN / 256, KC, B), 256, 0, stream>>>(G, cspart, NN);
    finalize_cs<<<dim3(NN / 256, B), 256, 0, stream>>>(cspart, inv_cs, NN);
    wt_kernel<<<256, 256, 0, stream>>>(W, Wt);
    if (big) cvtT<<<dim3(32, 32, 8), 256, 0, stream>>>(G, GT);

    const long sNT = 256L * NN;
    // NeT = (H@W)^T : A=H fp32 [b][2048][256]
    mgemm<EPI_NE, A_F32ROW><<<dim3(32, 4, 8), 256, 0, stream>>>(
        H, Wt, nullptr, nullptr, nullptr, NeT, nullptr, nullptr,
        256, 256, 2048L * 256, 0);
    // M1 = G@Ne -> M1bf + M1sT (scaled inv_rs)
    mgemm<EPI_M1, A_F32ROW><<<dim3(32, 4, 8), 256, 0, stream>>>(
        G, NeT, nullptr, nullptr, M1bf, M1sT, nullptr, inv_rs,
        2048, 2048, GSTR, sNT);
    // P2: A=G^T, B=[NeT ; M1sT] -> M2sT (scaled inv_cs) + out1 + out2
    if (big)
        mgemm<EPI_P2, A_DMA><<<dim3(32, 8, 8), 256, 0, stream>>>(
            GT, NeT, M1sT, M1bf, nullptr, M2sT, out, inv_cs,
            2048, 2048, GSTR, sNT);
    else
        mgemm<EPI_P2, A_F32TRANS><<<dim3(32, 8, 8), 256, 0, stream>>>(
            G, NeT, M1sT, M1bf, nullptr, M2sT, out, inv_cs,
            2048, 2048, GSTR, sNT);
    // out3 = relu(G @ M2s)
    mgemm<EPI_O3, A_F32ROW><<<dim3(32, 4, 8), 256, 0, stream>>>(
        G, M2sT, nullptr, nullptr, nullptr, nullptr, out, nullptr,
        2048, 2048, GSTR, sNT);
}

// Round 6
// 394.894 us; speedup vs baseline: 3.2083x; 1.2552x over previous
//
#include <hip/hip_runtime.h>
#include <hip/hip_bf16.h>

// B=8, N=2048, DIN=256, DOUT=256
// Ne = H@W ; M1 = G@Ne ; M2 = G^T@Ne
// out[:,0:256]   = relu(0.5*(M1+M2))
// out[:,256:512] = relu(G^T @ (M1 * inv_rs))
// out[:,512:768] = relu(G   @ (M2 * inv_cs))

constexpr int NN = 2048;
constexpr long GSTR = (long)NN * NN;

using frag8   = __attribute__((ext_vector_type(8))) short;   // 8 bf16
using floatx4 = __attribute__((ext_vector_type(4))) float;
using ush8    = __attribute__((ext_vector_type(8))) unsigned short;

__device__ inline unsigned short f2bf(float x) {
    unsigned u = __float_as_uint(x);
    u += 0x7FFF + ((u >> 16) & 1);   // RNE
    return (unsigned short)(u >> 16);
}
__device__ inline float bf2f(unsigned short h) {
    return __uint_as_float((unsigned)h << 16);
}
__device__ inline ushort2 pk2(float a, float b) {
    union { __hip_bfloat162 h; ushort2 u; } cv;
    cv.h = __float22bfloat162_rn(float2{a, b});
    return cv.u;
}
__device__ inline void gload_lds16(const void* g, void* l) {
    __builtin_amdgcn_global_load_lds(
        (const __attribute__((address_space(1))) void*)g,
        (__attribute__((address_space(3))) void*)l, 16, 0, 0);
}

enum { EPI_NE = 0, EPI_M1 = 1, EPI_P2 = 2, EPI_O3 = 3 };
enum { A_F32ROW = 0, A_DMA = 1 };

// C[i,j] = sum_k Alog[i,k] * Bt[j,k]; Bt bf16 [n][K] staged via global_load_lds.
// LDS layout (As/Bs): row stride 64 shorts; 16B chunk c of row r at slot c^(r&7).
// Tile 64x64, BK=64, 4 waves in 2x2 (wave = 32x32 = 2x2 MFMA 16x16x32).
// Batch-local i0b always; bb = blockIdx.z (R4/R5-proven indexing).
template <int EPI, int AMODE>
__global__ __launch_bounds__(256) void mgemm(
    const void* __restrict__ Aptr,
    const unsigned short* __restrict__ B0,
    const unsigned short* __restrict__ B1,     // P2: M1sT (j0>=256 B-source + out1 reconstruct)
    const float* __restrict__ rsraw,           // P2: raw row sums (un-scale M1sT)
    unsigned short* __restrict__ CsT,          // transposed bf16 out [256][2048]
    float* __restrict__ outp,                  // fp32 out base (stride 768)
    const float* __restrict__ scale,           // M1: inv_rs ; P2: inv_cs
    int K, int lda, long strideA, long sB)
{
    __shared__ __align__(16) unsigned short As[64 * 64];
    __shared__ __align__(16) unsigned short Bs[64 * 64];

    const int t   = threadIdx.x;
    const int i0b = blockIdx.x * 64;     // batch-local row tile
    const int j0  = blockIdx.y * 64;
    const int bb  = blockIdx.z;

    const unsigned short* Btb =
        ((EPI == EPI_P2 && j0 >= 256) ? B1 + (long)(j0 - 256) * K
                                      : B0 + (long)j0 * K) + (long)bb * sB;

    const int w = t >> 6, l = t & 63;
    const int wm = w >> 1, wn = w & 1;
    const int quad = l >> 4, c15 = l & 15;

    const int lr  = l >> 3, ls = l & 7;  // DMA: row-in-8, slot
    const int ar  = t >> 2;              // F32ROW: row 0..63
    const int ac0 = (t & 3) * 2;         // F32ROW: chunk base {0,2,4,6}

    floatx4 acc[2][2] = {};

    for (int k0 = 0; k0 < K; k0 += 64) {
        // ---- stage A
        if constexpr (AMODE == A_DMA) {
            const unsigned short* Au = (const unsigned short*)Aptr + (long)bb * strideA;
            #pragma unroll
            for (int q = 0; q < 2; ++q) {
                const int rt = w * 16 + q * 8;
                gload_lds16(Au + (long)(i0b + rt + lr) * lda + k0 + ((ls ^ lr) << 3),
                            &As[rt * 64]);
            }
        } else {  // A_F32ROW (NE over fp32 H)
            const float* Af = (const float*)Aptr + (long)bb * strideA;
            const float* ap = Af + (long)(i0b + ar) * lda + k0 + ac0 * 8;
            const float4 x0 = *(const float4*)(ap + 0);
            const float4 x1 = *(const float4*)(ap + 4);
            const float4 x2 = *(const float4*)(ap + 8);
            const float4 x3 = *(const float4*)(ap + 12);
            union { ush8 v; ushort2 u2[4]; } p0, p1;
            p0.u2[0] = pk2(x0.x, x0.y); p0.u2[1] = pk2(x0.z, x0.w);
            p0.u2[2] = pk2(x1.x, x1.y); p0.u2[3] = pk2(x1.z, x1.w);
            p1.u2[0] = pk2(x2.x, x2.y); p1.u2[1] = pk2(x2.z, x2.w);
            p1.u2[2] = pk2(x3.x, x3.y); p1.u2[3] = pk2(x3.z, x3.w);
            const int sw = ar & 7;
            *(ush8*)&As[ar * 64 + ((ac0 ^ sw) << 3)]       = p0.v;
            *(ush8*)&As[ar * 64 + (((ac0 + 1) ^ sw) << 3)] = p1.v;
        }
        // ---- stage B (always DMA)
        #pragma unroll
        for (int q = 0; q < 2; ++q) {
            const int rt = w * 16 + q * 8;
            gload_lds16(Btb + (long)(rt + lr) * K + k0 + ((ls ^ lr) << 3),
                        &Bs[rt * 64]);
        }
        __syncthreads();

        #pragma unroll
        for (int ks = 0; ks < 2; ++ks) {
            frag8 af[2], bfv[2];
            const int swr = c15 & 7;
            #pragma unroll
            for (int mt = 0; mt < 2; ++mt)
                af[mt] = *(const frag8*)&As[(wm * 32 + mt * 16 + c15) * 64
                                            + (((ks * 4 + quad) ^ swr) << 3)];
            #pragma unroll
            for (int nt = 0; nt < 2; ++nt)
                bfv[nt] = *(const frag8*)&Bs[(wn * 32 + nt * 16 + c15) * 64
                                             + (((ks * 4 + quad) ^ swr) << 3)];
            #pragma unroll
            for (int mt = 0; mt < 2; ++mt)
                #pragma unroll
                for (int nt = 0; nt < 2; ++nt)
                    acc[mt][nt] = __builtin_amdgcn_mfma_f32_16x16x32_bf16(
                        af[mt], bfv[nt], acc[mt][nt], 0, 0, 0);
        }
        __syncthreads();
    }

    // ---- epilogue: C/D layout col=lane&15, row=quad*4+reg
    const long rowb = (long)bb * NN;
    #pragma unroll
    for (int mt = 0; mt < 2; ++mt) {
        const int il = wm * 32 + mt * 16 + quad * 4;
        const int ib = i0b + il;
        float4 s4 = make_float4(1.f, 1.f, 1.f, 1.f);
        if constexpr (EPI == EPI_M1) s4 = *(const float4*)(scale + rowb + ib);
        if constexpr (EPI == EPI_P2) {
            if (j0 < 256) s4 = *(const float4*)(scale + rowb + ib);
        }
        #pragma unroll
        for (int nt = 0; nt < 2; ++nt) {
            floatx4 v = acc[mt][nt];
            const int gj = j0 + wn * 32 + nt * 16 + c15;
            if constexpr (EPI == EPI_NE) {
                union { ushort4 v; ushort2 u2[2]; } p;
                p.u2[0] = pk2(v[0], v[1]); p.u2[1] = pk2(v[2], v[3]);
                *(ushort4*)(CsT + ((long)bb * 256 + gj) * 2048 + ib) = p.v;
            } else if constexpr (EPI == EPI_M1) {
                union { ushort4 v; ushort2 u2[2]; } p;
                p.u2[0] = pk2(v[0] * s4.x, v[1] * s4.y);
                p.u2[1] = pk2(v[2] * s4.z, v[3] * s4.w);
                *(ushort4*)(CsT + ((long)bb * 256 + gj) * 2048 + ib) = p.v;
            } else if constexpr (EPI == EPI_P2) {
                if (j0 < 256) {
                    union { ushort4 v; ushort2 u2[2]; } p;
                    p.u2[0] = pk2(v[0] * s4.x, v[1] * s4.y);
                    p.u2[1] = pk2(v[2] * s4.z, v[3] * s4.w);
                    *(ushort4*)(CsT + ((long)bb * 256 + gj) * 2048 + ib) = p.v;
                    // out1: reconstruct M1 = M1sT * rs_raw
                    const float4 rr = *(const float4*)(rsraw + rowb + ib);
                    const ushort4 m1p = *(const ushort4*)(B1 + ((long)bb * 256 + gj) * 2048 + ib);
                    const float m1v[4] = {bf2f(m1p.x) * rr.x, bf2f(m1p.y) * rr.y,
                                          bf2f(m1p.z) * rr.z, bf2f(m1p.w) * rr.w};
                    #pragma unroll
                    for (int r = 0; r < 4; ++r)
                        outp[(rowb + ib + r) * 768 + gj] = fmaxf(0.5f * (v[r] + m1v[r]), 0.f);
                } else {
                    #pragma unroll
                    for (int r = 0; r < 4; ++r)
                        outp[(rowb + ib + r) * 768 + gj] = fmaxf(v[r], 0.f);  // gj in [256,512)
                }
            } else {  // EPI_O3
                #pragma unroll
                for (int r = 0; r < 4; ++r)
                    outp[(rowb + ib + r) * 768 + 512 + gj] = fmaxf(v[r], 0.f);
            }
        }
    }
}

// ---- fused: G fp32 -> Gbf + GbfT + row/col partial sums (no atomics) ----
// grid (32 j-tiles, 32 i-tiles, 8 b), 256 threads, 64x64 tile per block.
__global__ __launch_bounds__(256) void cvt_g(
    const float* __restrict__ G,
    unsigned short* __restrict__ Gbf, unsigned short* __restrict__ GbfT,
    float* __restrict__ prs, float* __restrict__ pcs)
{
    __shared__ float Tf[64 * 65];
    __shared__ float cp[4][64];
    const int b = blockIdx.z;
    const int j0 = blockIdx.x * 64, i0 = blockIdx.y * 64;
    const int t = threadIdx.x;
    const int r = t >> 2, cb = (t & 3) * 16;

    float x[16];
    const long gbase = (long)b * GSTR + (long)(i0 + r) * NN + j0 + cb;
    #pragma unroll
    for (int q = 0; q < 4; ++q)
        *(float4*)&x[q * 4] = *(const float4*)(G + gbase + q * 4);

    // Gbf (row-major bf16)
    union { ush8 v; ushort2 u2[4]; } pa, pb;
    #pragma unroll
    for (int q = 0; q < 4; ++q) pa.u2[q] = pk2(x[q * 2], x[q * 2 + 1]);
    #pragma unroll
    for (int q = 0; q < 4; ++q) pb.u2[q] = pk2(x[8 + q * 2], x[8 + q * 2 + 1]);
    *(ush8*)(Gbf + gbase)     = pa.v;
    *(ush8*)(Gbf + gbase + 8) = pb.v;

    // row partial (tile-local sum of 64 cols -> prs[b][jc][row])
    float sr = 0.f;
    #pragma unroll
    for (int j = 0; j < 16; ++j) sr += x[j];
    sr += __shfl_xor(sr, 1);
    sr += __shfl_xor(sr, 2);
    if ((t & 3) == 0) prs[((long)b * 32 + blockIdx.x) * NN + i0 + r] = sr;

    #pragma unroll
    for (int j = 0; j < 16; ++j) Tf[r * 65 + cb + j] = x[j];
    __syncthreads();

    // col partial
    {
        const int col = t & 63, seg = t >> 6;
        float sc = 0.f;
        #pragma unroll
        for (int rr = 0; rr < 16; ++rr) sc += Tf[(seg * 16 + rr) * 65 + col];
        cp[seg][col] = sc;
    }
    __syncthreads();
    if (t < 64)
        pcs[((long)b * 32 + blockIdx.y) * NN + j0 + t] =
            cp[0][t] + cp[1][t] + cp[2][t] + cp[3][t];

    // GbfT (transposed bf16)
    const int co = t >> 2, rb = (t & 3) * 16;
    unsigned short* dst = GbfT + (long)b * GSTR + (long)(j0 + co) * NN + i0 + rb;
    union { ush8 v; ushort2 u2[4]; } qa, qb;
    #pragma unroll
    for (int q = 0; q < 4; ++q)
        qa.u2[q] = pk2(Tf[(rb + q * 2) * 65 + co], Tf[(rb + q * 2 + 1) * 65 + co]);
    #pragma unroll
    for (int q = 0; q < 4; ++q)
        qb.u2[q] = pk2(Tf[(rb + 8 + q * 2) * 65 + co], Tf[(rb + 8 + q * 2 + 1) * 65 + co]);
    *(ush8*)(dst)     = qa.v;
    *(ush8*)(dst + 8) = qb.v;
}

// reduce partials: y=0 -> inv_rs + rs_raw ; y=1 -> inv_cs
__global__ __launch_bounds__(256) void finalize(
    const float* __restrict__ prs, const float* __restrict__ pcs,
    float* __restrict__ inv_rs, float* __restrict__ rs_raw,
    float* __restrict__ inv_cs)
{
    const int idx = blockIdx.x * 256 + threadIdx.x;   // 0..16383
    const int b = idx >> 11, i = idx & 2047;
    if (blockIdx.y == 0) {
        float s = 0.f;
        #pragma unroll
        for (int jc = 0; jc < 32; ++jc) s += prs[((long)b * 32 + jc) * NN + i];
        inv_rs[idx] = 1.0f / s;
        rs_raw[idx] = s;
    } else {
        float s = 0.f;
        #pragma unroll
        for (int jc = 0; jc < 32; ++jc) s += pcs[((long)b * 32 + jc) * NN + i];
        inv_cs[idx] = 1.0f / s;
    }
}

// Wt[j][k] = bf16(W[k][j])
__global__ __launch_bounds__(256) void wt_kernel(
    const float* __restrict__ W, unsigned short* __restrict__ Wt)
{
    const int j = threadIdx.x, k = blockIdx.x;
    Wt[(long)j * 256 + k] = f2bf(W[(long)k * 256 + j]);
}

extern "C" void kernel_launch(void* const* d_in, const int* in_sizes, int n_in,
                              void* d_out, int out_size, void* d_ws, size_t ws_size,
                              hipStream_t stream)
{
    constexpr int B = 8;
    const float* H = (const float*)d_in[0];
    const float* G = (const float*)d_in[1];
    const float* W = (const float*)d_in[2];
    float* out = (float*)d_out;

    unsigned short* ws16 = (unsigned short*)d_ws;
    unsigned short* Gbf  = ws16;                          // 33,554,432 shorts
    unsigned short* GbfT = Gbf  + (long)B * GSTR;         // 33,554,432
    unsigned short* Wt   = GbfT + (long)B * GSTR;         // 65,536
    unsigned short* NeT  = Wt   + 65536;                  // 4,194,304
    unsigned short* M1sT = NeT  + 4194304;                // 4,194,304
    unsigned short* M2sT = M1sT + 4194304;                // 4,194,304
    float* inv_rs = (float*)(M2sT + 4194304);             // 16384
    float* rs_raw = inv_rs + 16384;
    float* inv_cs = rs_raw + 16384;
    float* prs    = inv_cs + 16384;                       // 8*32*2048
    float* pcs    = prs + (long)B * 32 * NN;              // 8*32*2048
    // total ~164 MB (ws = 512 MiB, verified via harness fill WRITE_SIZE)

    cvt_g<<<dim3(32, 32, 8), 256, 0, stream>>>(G, Gbf, GbfT, prs, pcs);
    finalize<<<dim3(64, 2), 256, 0, stream>>>(prs, pcs, inv_rs, rs_raw, inv_cs);
    wt_kernel<<<256, 256, 0, stream>>>(W, Wt);

    const long sNT = 256L * NN;
    // NeT = (H@W)^T : A=H fp32 [b][2048][256]
    mgemm<EPI_NE, A_F32ROW><<<dim3(32, 4, 8), 256, 0, stream>>>(
        H, Wt, nullptr, nullptr, NeT, nullptr, nullptr,
        256, 256, 2048L * 256, 0);
    // M1sT = (G@Ne * inv_rs)^T
    mgemm<EPI_M1, A_DMA><<<dim3(32, 4, 8), 256, 0, stream>>>(
        Gbf, NeT, nullptr, nullptr, M1sT, nullptr, inv_rs,
        2048, 2048, GSTR, sNT);
    // P2: A=GbfT, B=[NeT ; M1sT] -> M2sT(scaled inv_cs) + out1 + out2
    mgemm<EPI_P2, A_DMA><<<dim3(32, 8, 8), 256, 0, stream>>>(
        GbfT, NeT, M1sT, rs_raw, M2sT, out, inv_cs,
        2048, 2048, GSTR, sNT);
    // out3 = relu(G @ M2s)
    mgemm<EPI_O3, A_DMA><<<dim3(32, 4, 8), 256, 0, stream>>>(
        Gbf, M2sT, nullptr, nullptr, nullptr, out, nullptr,
        2048, 2048, GSTR, sNT);
}

// Round 7
// 390.734 us; speedup vs baseline: 3.2424x; 1.0106x over previous
//
#include <hip/hip_runtime.h>
#include <hip/hip_bf16.h>

// B=8, N=2048, DIN=256, DOUT=256
// Ne = H@W ; M1 = G@Ne ; M2 = G^T@Ne
// out[:,0:256]   = relu(0.5*(M1+M2))
// out[:,256:512] = relu(G^T @ (M1 * inv_rs))
// out[:,512:768] = relu(G   @ (M2 * inv_cs))

constexpr int NN = 2048;
constexpr long GSTR = (long)NN * NN;

using frag8   = __attribute__((ext_vector_type(8))) short;   // 8 bf16
using floatx4 = __attribute__((ext_vector_type(4))) float;
using ush8    = __attribute__((ext_vector_type(8))) unsigned short;

__device__ inline unsigned short f2bf(float x) {
    unsigned u = __float_as_uint(x);
    u += 0x7FFF + ((u >> 16) & 1);   // RNE
    return (unsigned short)(u >> 16);
}
__device__ inline float bf2f(unsigned short h) {
    return __uint_as_float((unsigned)h << 16);
}
__device__ inline ushort2 pk2(float a, float b) {
    union { __hip_bfloat162 h; ushort2 u; } cv;
    cv.h = __float22bfloat162_rn(float2{a, b});
    return cv.u;
}
__device__ inline void gload_lds16(const void* g, void* l) {
    __builtin_amdgcn_global_load_lds(
        (const __attribute__((address_space(1))) void*)g,
        (__attribute__((address_space(3))) void*)l, 16, 0, 0);
}

enum { EPI_NE = 0, EPI_M1 = 1, EPI_P2 = 2, EPI_O3 = 3 };
enum { A_F32ROW = 0, A_DMA = 1 };

// C[i,j] = sum_k Alog[i,k] * Bt[j,k]; Bt bf16 [n][K] staged via global_load_lds.
// LDS (As/Bs): row stride 64 shorts; 16B chunk c of row r at slot c^(r&7)
//   -> fragment ds_read_b128 2-way (free), staging fully coalesced. (R6: 0 conflicts)
// Tile TM x 64, BK=64, 4 waves in 2x2 (wave = TM/2 rows x 32 cols).
template <int EPI, int AMODE, int TM>
__global__ __launch_bounds__(256) void mgemm(
    const void* __restrict__ Aptr,
    const unsigned short* __restrict__ B0,
    const unsigned short* __restrict__ B1,     // P2: M1sT (j0>=256 B-source + out1 reconstruct)
    const float* __restrict__ rsraw,           // P2: raw row sums (un-scale M1sT)
    unsigned short* __restrict__ CsT,          // transposed bf16 out [256][2048]
    float* __restrict__ outp,                  // fp32 out base (stride 768)
    const float* __restrict__ scale,           // M1: inv_rs ; P2: inv_cs
    int K, int lda, long strideA, long sB)
{
    constexpr int MF = TM / 32;                // m-frags per wave
    __shared__ __align__(16) unsigned short As[TM * 64];
    __shared__ __align__(16) unsigned short Bs[64 * 64];

    const int t   = threadIdx.x;
    const int i0b = blockIdx.x * TM;     // batch-local row tile
    const int j0  = blockIdx.y * 64;
    const int bb  = blockIdx.z;

    const unsigned short* Btb =
        ((EPI == EPI_P2 && j0 >= 256) ? B1 + (long)(j0 - 256) * K
                                      : B0 + (long)j0 * K) + (long)bb * sB;

    const int w = t >> 6, l = t & 63;
    const int wm = w >> 1, wn = w & 1;
    const int quad = l >> 4, c15 = l & 15;

    const int lr  = l >> 3, ls = l & 7;  // DMA: row-in-8, slot

    floatx4 acc[MF][2] = {};

    for (int k0 = 0; k0 < K; k0 += 64) {
        // ---- stage A
        if constexpr (AMODE == A_DMA) {
            const unsigned short* Au = (const unsigned short*)Aptr + (long)bb * strideA;
            #pragma unroll
            for (int q = 0; q < TM / 32; ++q) {
                const int rt = q * 32 + w * 8;
                gload_lds16(Au + (long)(i0b + rt + lr) * lda + k0 + ((ls ^ lr) << 3),
                            &As[rt * 64]);
            }
        } else {  // A_F32ROW (NE over fp32 H), TM=64: 16 floats/thread
            const float* Af = (const float*)Aptr + (long)bb * strideA;
            const int ar  = t >> 2;
            const int ac0 = (t & 3) * 2;
            const float* ap = Af + (long)(i0b + ar) * lda + k0 + ac0 * 8;
            const float4 x0 = *(const float4*)(ap + 0);
            const float4 x1 = *(const float4*)(ap + 4);
            const float4 x2 = *(const float4*)(ap + 8);
            const float4 x3 = *(const float4*)(ap + 12);
            union { ush8 v; ushort2 u2[4]; } p0, p1;
            p0.u2[0] = pk2(x0.x, x0.y); p0.u2[1] = pk2(x0.z, x0.w);
            p0.u2[2] = pk2(x1.x, x1.y); p0.u2[3] = pk2(x1.z, x1.w);
            p1.u2[0] = pk2(x2.x, x2.y); p1.u2[1] = pk2(x2.z, x2.w);
            p1.u2[2] = pk2(x3.x, x3.y); p1.u2[3] = pk2(x3.z, x3.w);
            const int sw = ar & 7;
            *(ush8*)&As[ar * 64 + ((ac0 ^ sw) << 3)]       = p0.v;
            *(ush8*)&As[ar * 64 + (((ac0 + 1) ^ sw) << 3)] = p1.v;
        }
        // ---- stage B (always DMA)
        #pragma unroll
        for (int q = 0; q < 2; ++q) {
            const int rt = w * 16 + q * 8;
            gload_lds16(Btb + (long)(rt + lr) * K + k0 + ((ls ^ lr) << 3),
                        &Bs[rt * 64]);
        }
        __syncthreads();

        #pragma unroll
        for (int ks = 0; ks < 2; ++ks) {
            frag8 af[MF], bfv[2];
            const int swr = c15 & 7;
            #pragma unroll
            for (int mt = 0; mt < MF; ++mt)
                af[mt] = *(const frag8*)&As[(wm * (TM / 2) + mt * 16 + c15) * 64
                                            + (((ks * 4 + quad) ^ swr) << 3)];
            #pragma unroll
            for (int nt = 0; nt < 2; ++nt)
                bfv[nt] = *(const frag8*)&Bs[(wn * 32 + nt * 16 + c15) * 64
                                             + (((ks * 4 + quad) ^ swr) << 3)];
            #pragma unroll
            for (int mt = 0; mt < MF; ++mt)
                #pragma unroll
                for (int nt = 0; nt < 2; ++nt)
                    acc[mt][nt] = __builtin_amdgcn_mfma_f32_16x16x32_bf16(
                        af[mt], bfv[nt], acc[mt][nt], 0, 0, 0);
        }
        __syncthreads();
    }

    // ---- epilogue: C/D layout col=lane&15, row=quad*4+reg
    const long rowb = (long)bb * NN;
    #pragma unroll
    for (int mt = 0; mt < MF; ++mt) {
        const int il = wm * (TM / 2) + mt * 16 + quad * 4;
        const int ib = i0b + il;
        float4 s4 = make_float4(1.f, 1.f, 1.f, 1.f);
        if constexpr (EPI == EPI_M1) s4 = *(const float4*)(scale + rowb + ib);
        if constexpr (EPI == EPI_P2) {
            if (j0 < 256) s4 = *(const float4*)(scale + rowb + ib);
        }
        #pragma unroll
        for (int nt = 0; nt < 2; ++nt) {
            floatx4 v = acc[mt][nt];
            const int gj = j0 + wn * 32 + nt * 16 + c15;
            if constexpr (EPI == EPI_NE) {
                union { ushort4 v; ushort2 u2[2]; } p;
                p.u2[0] = pk2(v[0], v[1]); p.u2[1] = pk2(v[2], v[3]);
                *(ushort4*)(CsT + ((long)bb * 256 + gj) * 2048 + ib) = p.v;
            } else if constexpr (EPI == EPI_M1) {
                union { ushort4 v; ushort2 u2[2]; } p;
                p.u2[0] = pk2(v[0] * s4.x, v[1] * s4.y);
                p.u2[1] = pk2(v[2] * s4.z, v[3] * s4.w);
                *(ushort4*)(CsT + ((long)bb * 256 + gj) * 2048 + ib) = p.v;
            } else if constexpr (EPI == EPI_P2) {
                if (j0 < 256) {
                    union { ushort4 v; ushort2 u2[2]; } p;
                    p.u2[0] = pk2(v[0] * s4.x, v[1] * s4.y);
                    p.u2[1] = pk2(v[2] * s4.z, v[3] * s4.w);
                    *(ushort4*)(CsT + ((long)bb * 256 + gj) * 2048 + ib) = p.v;
                    // out1: reconstruct M1 = M1sT * rs_raw
                    const float4 rr = *(const float4*)(rsraw + rowb + ib);
                    const ushort4 m1p = *(const ushort4*)(B1 + ((long)bb * 256 + gj) * 2048 + ib);
                    const float m1v[4] = {bf2f(m1p.x) * rr.x, bf2f(m1p.y) * rr.y,
                                          bf2f(m1p.z) * rr.z, bf2f(m1p.w) * rr.w};
                    #pragma unroll
                    for (int r = 0; r < 4; ++r)
                        outp[(rowb + ib + r) * 768 + gj] = fmaxf(0.5f * (v[r] + m1v[r]), 0.f);
                } else {
                    #pragma unroll
                    for (int r = 0; r < 4; ++r)
                        outp[(rowb + ib + r) * 768 + gj] = fmaxf(v[r], 0.f);  // gj in [256,512)
                }
            } else {  // EPI_O3
                #pragma unroll
                for (int r = 0; r < 4; ++r)
                    outp[(rowb + ib + r) * 768 + 512 + gj] = fmaxf(v[r], 0.f);
            }
        }
    }
}

// ---- fused: G fp32 -> Gbf + GbfT + row/col partial sums (no atomics) ----
__global__ __launch_bounds__(256) void cvt_g(
    const float* __restrict__ G,
    unsigned short* __restrict__ Gbf, unsigned short* __restrict__ GbfT,
    float* __restrict__ prs, float* __restrict__ pcs)
{
    __shared__ float Tf[64 * 65];
    __shared__ float cp[4][64];
    const int b = blockIdx.z;
    const int j0 = blockIdx.x * 64, i0 = blockIdx.y * 64;
    const int t = threadIdx.x;
    const int r = t >> 2, cb = (t & 3) * 16;

    float x[16];
    const long gbase = (long)b * GSTR + (long)(i0 + r) * NN + j0 + cb;
    #pragma unroll
    for (int q = 0; q < 4; ++q)
        *(float4*)&x[q * 4] = *(const float4*)(G + gbase + q * 4);

    union { ush8 v; ushort2 u2[4]; } pa, pb;
    #pragma unroll
    for (int q = 0; q < 4; ++q) pa.u2[q] = pk2(x[q * 2], x[q * 2 + 1]);
    #pragma unroll
    for (int q = 0; q < 4; ++q) pb.u2[q] = pk2(x[8 + q * 2], x[8 + q * 2 + 1]);
    *(ush8*)(Gbf + gbase)     = pa.v;
    *(ush8*)(Gbf + gbase + 8) = pb.v;

    float sr = 0.f;
    #pragma unroll
    for (int j = 0; j < 16; ++j) sr += x[j];
    sr += __shfl_xor(sr, 1);
    sr += __shfl_xor(sr, 2);
    if ((t & 3) == 0) prs[((long)b * 32 + blockIdx.x) * NN + i0 + r] = sr;

    #pragma unroll
    for (int j = 0; j < 16; ++j) Tf[r * 65 + cb + j] = x[j];
    __syncthreads();

    {
        const int col = t & 63, seg = t >> 6;
        float sc = 0.f;
        #pragma unroll
        for (int rr = 0; rr < 16; ++rr) sc += Tf[(seg * 16 + rr) * 65 + col];
        cp[seg][col] = sc;
    }
    __syncthreads();
    if (t < 64)
        pcs[((long)b * 32 + blockIdx.y) * NN + j0 + t] =
            cp[0][t] + cp[1][t] + cp[2][t] + cp[3][t];

    const int co = t >> 2, rb = (t & 3) * 16;
    unsigned short* dst = GbfT + (long)b * GSTR + (long)(j0 + co) * NN + i0 + rb;
    union { ush8 v; ushort2 u2[4]; } qa, qb;
    #pragma unroll
    for (int q = 0; q < 4; ++q)
        qa.u2[q] = pk2(Tf[(rb + q * 2) * 65 + co], Tf[(rb + q * 2 + 1) * 65 + co]);
    #pragma unroll
    for (int q = 0; q < 4; ++q)
        qb.u2[q] = pk2(Tf[(rb + 8 + q * 2) * 65 + co], Tf[(rb + 8 + q * 2 + 1) * 65 + co]);
    *(ush8*)(dst)     = qa.v;
    *(ush8*)(dst + 8) = qb.v;
}

// reduce partials + W transpose: y=0 -> inv_rs+rs_raw ; y=1 -> inv_cs ; y=2 -> Wt
__global__ __launch_bounds__(256) void finalize(
    const float* __restrict__ prs, const float* __restrict__ pcs,
    float* __restrict__ inv_rs, float* __restrict__ rs_raw,
    float* __restrict__ inv_cs,
    const float* __restrict__ W, unsigned short* __restrict__ Wt)
{
    const int idx = blockIdx.x * 256 + threadIdx.x;   // 0..16383
    if (blockIdx.y == 0) {
        const int b = idx >> 11, i = idx & 2047;
        float s = 0.f;
        #pragma unroll
        for (int jc = 0; jc < 32; ++jc) s += prs[((long)b * 32 + jc) * NN + i];
        inv_rs[idx] = 1.0f / s;
        rs_raw[idx] = s;
    } else if (blockIdx.y == 1) {
        const int b = idx >> 11, i = idx & 2047;
        float s = 0.f;
        #pragma unroll
        for (int jc = 0; jc < 32; ++jc) s += pcs[((long)b * 32 + jc) * NN + i];
        inv_cs[idx] = 1.0f / s;
    } else {
        #pragma unroll
        for (int e = 0; e < 4; ++e) {
            const int flat = idx * 4 + e;              // 0..65535
            const int j = flat >> 8, k = flat & 255;
            Wt[flat] = f2bf(W[(long)k * 256 + j]);
        }
    }
}

extern "C" void kernel_launch(void* const* d_in, const int* in_sizes, int n_in,
                              void* d_out, int out_size, void* d_ws, size_t ws_size,
                              hipStream_t stream)
{
    constexpr int B = 8;
    const float* H = (const float*)d_in[0];
    const float* G = (const float*)d_in[1];
    const float* W = (const float*)d_in[2];
    float* out = (float*)d_out;

    unsigned short* ws16 = (unsigned short*)d_ws;
    unsigned short* Gbf  = ws16;                          // 33,554,432 shorts
    unsigned short* GbfT = Gbf  + (long)B * GSTR;         // 33,554,432
    unsigned short* Wt   = GbfT + (long)B * GSTR;         // 65,536
    unsigned short* NeT  = Wt   + 65536;                  // 4,194,304
    unsigned short* M1sT = NeT  + 4194304;                // 4,194,304
    unsigned short* M2sT = M1sT + 4194304;                // 4,194,304
    float* inv_rs = (float*)(M2sT + 4194304);             // 16384
    float* rs_raw = inv_rs + 16384;
    float* inv_cs = rs_raw + 16384;
    float* prs    = inv_cs + 16384;                       // 8*32*2048
    float* pcs    = prs + (long)B * 32 * NN;              // 8*32*2048
    // total ~164 MB (ws = 512 MiB per harness fill WRITE_SIZE)

    cvt_g<<<dim3(32, 32, 8), 256, 0, stream>>>(G, Gbf, GbfT, prs, pcs);
    finalize<<<dim3(64, 3), 256, 0, stream>>>(prs, pcs, inv_rs, rs_raw, inv_cs, W, Wt);

    const long sNT = 256L * NN;
    // NeT = (H@W)^T : A=H fp32 [b][2048][256]  (TM=64, proven F32ROW staging)
    mgemm<EPI_NE, A_F32ROW, 64><<<dim3(32, 4, 8), 256, 0, stream>>>(
        H, Wt, nullptr, nullptr, NeT, nullptr, nullptr,
        256, 256, 2048L * 256, 0);
    // M1sT = (G@Ne * inv_rs)^T   (TM=128 DMA)
    mgemm<EPI_M1, A_DMA, 128><<<dim3(16, 4, 8), 256, 0, stream>>>(
        Gbf, NeT, nullptr, nullptr, M1sT, nullptr, inv_rs,
        2048, 2048, GSTR, sNT);
    // P2: A=GbfT, B=[NeT ; M1sT] -> M2sT(scaled inv_cs) + out1 + out2
    mgemm<EPI_P2, A_DMA, 128><<<dim3(16, 8, 8), 256, 0, stream>>>(
        GbfT, NeT, M1sT, rs_raw, M2sT, out, inv_cs,
        2048, 2048, GSTR, sNT);
    // out3 = relu(G @ M2s)
    mgemm<EPI_O3, A_DMA, 128><<<dim3(16, 4, 8), 256, 0, stream>>>(
        Gbf, M2sT, nullptr, nullptr, nullptr, out, nullptr,
        2048, 2048, GSTR, sNT);
}

// Round 8
// 383.433 us; speedup vs baseline: 3.3042x; 1.0190x over previous
//
#include <hip/hip_runtime.h>
#include <hip/hip_bf16.h>

// B=8, N=2048, DIN=256, DOUT=256
// Ne = H@W ; M1 = G@Ne ; M2 = G^T@Ne
// out[:,0:256]   = relu(0.5*(M1+M2))
// out[:,256:512] = relu(G^T @ (M1 * inv_rs))
// out[:,512:768] = relu(G   @ (M2 * inv_cs))

constexpr int NN = 2048;
constexpr long GSTR = (long)NN * NN;

using frag8   = __attribute__((ext_vector_type(8))) short;   // 8 bf16
using floatx4 = __attribute__((ext_vector_type(4))) float;
using ush8    = __attribute__((ext_vector_type(8))) unsigned short;

__device__ inline unsigned short f2bf(float x) {
    unsigned u = __float_as_uint(x);
    u += 0x7FFF + ((u >> 16) & 1);   // RNE
    return (unsigned short)(u >> 16);
}
__device__ inline float bf2f(unsigned short h) {
    return __uint_as_float((unsigned)h << 16);
}
__device__ inline ushort2 pk2(float a, float b) {
    union { __hip_bfloat162 h; ushort2 u; } cv;
    cv.h = __float22bfloat162_rn(float2{a, b});
    return cv.u;
}
__device__ inline void gload_lds16(const void* g, void* l) {
    __builtin_amdgcn_global_load_lds(
        (const __attribute__((address_space(1))) void*)g,
        (__attribute__((address_space(3))) void*)l, 16, 0, 0);
}

enum { EPI_NE = 0, EPI_M1 = 1, EPI_P2 = 2, EPI_O3 = 3 };
enum { A_F32ROW = 0, A_DMA = 1 };

// C[i,j] = sum_k Alog[i,k] * Bt[j,k]; Bt bf16 [n][K] staged via global_load_lds.
// LDS (As/Bs): row stride 64 shorts; 16B chunk c of row r at slot c^(r&7)
//   -> fragment ds_read_b128 2-way (free), staging fully coalesced. (R6: 0 conflicts)
// Tile TM x 64, BK=64, 4 waves in 2x2 (wave = TM/2 rows x 32 cols).
template <int EPI, int AMODE, int TM>
__global__ __launch_bounds__(256) void mgemm(
    const void* __restrict__ Aptr,
    const unsigned short* __restrict__ B0,
    const unsigned short* __restrict__ B1,     // P2: M1sT (j0>=256 B-source + out1 reconstruct)
    const float* __restrict__ rsraw,           // P2: raw row sums (un-scale M1sT)
    unsigned short* __restrict__ CsT,          // transposed bf16 out [256][2048]
    float* __restrict__ outp,                  // fp32 out base (stride 768)
    const float* __restrict__ scale,           // M1: inv_rs ; P2: inv_cs
    int K, int lda, long strideA, long sB)
{
    constexpr int MF = TM / 32;                // m-frags per wave
    __shared__ __align__(16) unsigned short As[TM * 64];
    __shared__ __align__(16) unsigned short Bs[64 * 64];

    const int t   = threadIdx.x;
    const int i0b = blockIdx.x * TM;     // batch-local row tile
    const int j0  = blockIdx.y * 64;
    const int bb  = blockIdx.z;

    const unsigned short* Btb =
        ((EPI == EPI_P2 && j0 >= 256) ? B1 + (long)(j0 - 256) * K
                                      : B0 + (long)j0 * K) + (long)bb * sB;

    const int w = t >> 6, l = t & 63;
    const int wm = w >> 1, wn = w & 1;
    const int quad = l >> 4, c15 = l & 15;

    const int lr  = l >> 3, ls = l & 7;  // DMA: row-in-8, slot

    floatx4 acc[MF][2] = {};

    for (int k0 = 0; k0 < K; k0 += 64) {
        // ---- stage A
        if constexpr (AMODE == A_DMA) {
            const unsigned short* Au = (const unsigned short*)Aptr + (long)bb * strideA;
            #pragma unroll
            for (int q = 0; q < TM / 32; ++q) {
                const int rt = q * 32 + w * 8;
                gload_lds16(Au + (long)(i0b + rt + lr) * lda + k0 + ((ls ^ lr) << 3),
                            &As[rt * 64]);
            }
        } else {  // A_F32ROW (NE over fp32 H), TM=64: 16 floats/thread
            const float* Af = (const float*)Aptr + (long)bb * strideA;
            const int ar  = t >> 2;
            const int ac0 = (t & 3) * 2;
            const float* ap = Af + (long)(i0b + ar) * lda + k0 + ac0 * 8;
            const float4 x0 = *(const float4*)(ap + 0);
            const float4 x1 = *(const float4*)(ap + 4);
            const float4 x2 = *(const float4*)(ap + 8);
            const float4 x3 = *(const float4*)(ap + 12);
            union { ush8 v; ushort2 u2[4]; } p0, p1;
            p0.u2[0] = pk2(x0.x, x0.y); p0.u2[1] = pk2(x0.z, x0.w);
            p0.u2[2] = pk2(x1.x, x1.y); p0.u2[3] = pk2(x1.z, x1.w);
            p1.u2[0] = pk2(x2.x, x2.y); p1.u2[1] = pk2(x2.z, x2.w);
            p1.u2[2] = pk2(x3.x, x3.y); p1.u2[3] = pk2(x3.z, x3.w);
            const int sw = ar & 7;
            *(ush8*)&As[ar * 64 + ((ac0 ^ sw) << 3)]       = p0.v;
            *(ush8*)&As[ar * 64 + (((ac0 + 1) ^ sw) << 3)] = p1.v;
        }
        // ---- stage B (always DMA)
        #pragma unroll
        for (int q = 0; q < 2; ++q) {
            const int rt = w * 16 + q * 8;
            gload_lds16(Btb + (long)(rt + lr) * K + k0 + ((ls ^ lr) << 3),
                        &Bs[rt * 64]);
        }
        __syncthreads();

        #pragma unroll
        for (int ks = 0; ks < 2; ++ks) {
            frag8 af[MF], bfv[2];
            const int swr = c15 & 7;
            #pragma unroll
            for (int mt = 0; mt < MF; ++mt)
                af[mt] = *(const frag8*)&As[(wm * (TM / 2) + mt * 16 + c15) * 64
                                            + (((ks * 4 + quad) ^ swr) << 3)];
            #pragma unroll
            for (int nt = 0; nt < 2; ++nt)
                bfv[nt] = *(const frag8*)&Bs[(wn * 32 + nt * 16 + c15) * 64
                                             + (((ks * 4 + quad) ^ swr) << 3)];
            #pragma unroll
            for (int mt = 0; mt < MF; ++mt)
                #pragma unroll
                for (int nt = 0; nt < 2; ++nt)
                    acc[mt][nt] = __builtin_amdgcn_mfma_f32_16x16x32_bf16(
                        af[mt], bfv[nt], acc[mt][nt], 0, 0, 0);
        }
        __syncthreads();
    }

    // ---- epilogue: C/D layout col=lane&15, row=quad*4+reg
    const long rowb = (long)bb * NN;
    #pragma unroll
    for (int mt = 0; mt < MF; ++mt) {
        const int il = wm * (TM / 2) + mt * 16 + quad * 4;
        const int ib = i0b + il;
        float4 s4 = make_float4(1.f, 1.f, 1.f, 1.f);
        if constexpr (EPI == EPI_M1) s4 = *(const float4*)(scale + rowb + ib);
        if constexpr (EPI == EPI_P2) {
            if (j0 < 256) s4 = *(const float4*)(scale + rowb + ib);
        }
        #pragma unroll
        for (int nt = 0; nt < 2; ++nt) {
            floatx4 v = acc[mt][nt];
            const int gj = j0 + wn * 32 + nt * 16 + c15;
            if constexpr (EPI == EPI_NE) {
                union { ushort4 v; ushort2 u2[2]; } p;
                p.u2[0] = pk2(v[0], v[1]); p.u2[1] = pk2(v[2], v[3]);
                *(ushort4*)(CsT + ((long)bb * 256 + gj) * 2048 + ib) = p.v;
            } else if constexpr (EPI == EPI_M1) {
                union { ushort4 v; ushort2 u2[2]; } p;
                p.u2[0] = pk2(v[0] * s4.x, v[1] * s4.y);
                p.u2[1] = pk2(v[2] * s4.z, v[3] * s4.w);
                *(ushort4*)(CsT + ((long)bb * 256 + gj) * 2048 + ib) = p.v;
            } else if constexpr (EPI == EPI_P2) {
                if (j0 < 256) {
                    union { ushort4 v; ushort2 u2[2]; } p;
                    p.u2[0] = pk2(v[0] * s4.x, v[1] * s4.y);
                    p.u2[1] = pk2(v[2] * s4.z, v[3] * s4.w);
                    *(ushort4*)(CsT + ((long)bb * 256 + gj) * 2048 + ib) = p.v;
                    // out1: reconstruct M1 = M1sT * rs_raw
                    const float4 rr = *(const float4*)(rsraw + rowb + ib);
                    const ushort4 m1p = *(const ushort4*)(B1 + ((long)bb * 256 + gj) * 2048 + ib);
                    const float m1v[4] = {bf2f(m1p.x) * rr.x, bf2f(m1p.y) * rr.y,
                                          bf2f(m1p.z) * rr.z, bf2f(m1p.w) * rr.w};
                    #pragma unroll
                    for (int r = 0; r < 4; ++r)
                        outp[(rowb + ib + r) * 768 + gj] = fmaxf(0.5f * (v[r] + m1v[r]), 0.f);
                } else {
                    #pragma unroll
                    for (int r = 0; r < 4; ++r)
                        outp[(rowb + ib + r) * 768 + gj] = fmaxf(v[r], 0.f);  // gj in [256,512)
                }
            } else {  // EPI_O3
                #pragma unroll
                for (int r = 0; r < 4; ++r)
                    outp[(rowb + ib + r) * 768 + 512 + gj] = fmaxf(v[r], 0.f);
            }
        }
    }
}

// ---- fused: G fp32 -> Gbf + GbfT + row/col partial sums ----
// 128x128 tile, 256 threads. All global streams >=256-B per-instruction segments.
// LDS: bf16 tile, row stride 136 shorts, rotation swizzle slot=(chunk+(row>>3))&15
//   -> phase-A b128 writes and phase-B scalar column reads both ~2-way (free).
__global__ __launch_bounds__(256) void cvt_g(
    const float* __restrict__ G,
    unsigned short* __restrict__ Gbf, unsigned short* __restrict__ GbfT,
    float* __restrict__ prs, float* __restrict__ pcs)
{
    __shared__ __align__(16) unsigned short Tb[128 * 136];
    __shared__ float cpw[4][128];

    const int b  = blockIdx.z;
    const int j0 = blockIdx.x * 128, i0 = blockIdx.y * 128;
    const int t  = threadIdx.x;
    const int c  = t & 15;        // 8-elem chunk along j (phase A) / i (phase B)
    const int rg = t >> 4;        // 0..15 row group
    const int w  = t >> 6, l16 = (t & 63) >> 4;

    float cs[8] = {};

    // ---- phase A: read G, write Gbf, stage LDS, row sums, col partials
    #pragma unroll
    for (int p = 0; p < 8; ++p) {
        const int row = p * 16 + rg;                 // tile-local i
        const long gb = (long)b * GSTR + (long)(i0 + row) * NN + j0 + c * 8;
        const float4 x0 = *(const float4*)(G + gb);
        const float4 x1 = *(const float4*)(G + gb + 4);
        union { ush8 v; ushort2 u2[4]; } pk;
        pk.u2[0] = pk2(x0.x, x0.y); pk.u2[1] = pk2(x0.z, x0.w);
        pk.u2[2] = pk2(x1.x, x1.y); pk.u2[3] = pk2(x1.z, x1.w);
        *(ush8*)(Gbf + gb) = pk.v;
        *(ush8*)&Tb[row * 136 + (((c + (row >> 3)) & 15) << 3)] = pk.v;

        float rp = x0.x + x0.y + x0.z + x0.w + x1.x + x1.y + x1.z + x1.w;
        rp += __shfl_xor(rp, 1);
        rp += __shfl_xor(rp, 2);
        rp += __shfl_xor(rp, 4);
        rp += __shfl_xor(rp, 8);
        if (c == 0) prs[((long)b * 16 + blockIdx.x) * NN + i0 + row] = rp;

        cs[0] += x0.x; cs[1] += x0.y; cs[2] += x0.z; cs[3] += x0.w;
        cs[4] += x1.x; cs[5] += x1.y; cs[6] += x1.z; cs[7] += x1.w;
    }

    // col partials: reduce across the wave's 4 row-groups, then cross-wave via LDS
    #pragma unroll
    for (int e = 0; e < 8; ++e) {
        cs[e] += __shfl_xor(cs[e], 16);
        cs[e] += __shfl_xor(cs[e], 32);
    }
    if (l16 == 0) {
        #pragma unroll
        for (int e = 0; e < 8; ++e) cpw[w][c * 8 + e] = cs[e];
    }
    __syncthreads();
    if (t < 128)
        pcs[((long)b * 16 + blockIdx.y) * NN + j0 + t] =
            cpw[0][t] + cpw[1][t] + cpw[2][t] + cpw[3][t];

    // ---- phase B: GbfT[j][i] from LDS (scalar column reads, 256-B stores)
    #pragma unroll
    for (int q = 0; q < 8; ++q) {
        const int jr = q * 16 + rg;                  // tile-local j
        const int sbase = ((jr >> 3) << 3);          // chunk(j)*8 pre-rotation
        union { ush8 v; unsigned short a[8]; } pk;
        #pragma unroll
        for (int r = 0; r < 8; ++r) {
            const int i = c * 8 + r;
            pk.a[r] = Tb[i * 136 + ((((jr >> 3) + c) & 15) << 3) + (jr & 7)];
        }
        (void)sbase;
        *(ush8*)(GbfT + (long)b * GSTR + (long)(j0 + jr) * NN + i0 + c * 8) = pk.v;
    }
}

// reduce partials + W transpose: y=0 -> inv_rs+rs_raw ; y=1 -> inv_cs ; y=2 -> Wt
__global__ __launch_bounds__(256) void finalize(
    const float* __restrict__ prs, const float* __restrict__ pcs,
    float* __restrict__ inv_rs, float* __restrict__ rs_raw,
    float* __restrict__ inv_cs,
    const float* __restrict__ W, unsigned short* __restrict__ Wt)
{
    const int idx = blockIdx.x * 256 + threadIdx.x;   // 0..16383
    if (blockIdx.y == 0) {
        const int b = idx >> 11, i = idx & 2047;
        float s = 0.f;
        #pragma unroll
        for (int jc = 0; jc < 16; ++jc) s += prs[((long)b * 16 + jc) * NN + i];
        inv_rs[idx] = 1.0f / s;
        rs_raw[idx] = s;
    } else if (blockIdx.y == 1) {
        const int b = idx >> 11, i = idx & 2047;
        float s = 0.f;
        #pragma unroll
        for (int ic = 0; ic < 16; ++ic) s += pcs[((long)b * 16 + ic) * NN + i];
        inv_cs[idx] = 1.0f / s;
    } else {
        #pragma unroll
        for (int e = 0; e < 4; ++e) {
            const int flat = idx * 4 + e;              // 0..65535
            const int j = flat >> 8, k = flat & 255;
            Wt[flat] = f2bf(W[(long)k * 256 + j]);
        }
    }
}

extern "C" void kernel_launch(void* const* d_in, const int* in_sizes, int n_in,
                              void* d_out, int out_size, void* d_ws, size_t ws_size,
                              hipStream_t stream)
{
    constexpr int B = 8;
    const float* H = (const float*)d_in[0];
    const float* G = (const float*)d_in[1];
    const float* W = (const float*)d_in[2];
    float* out = (float*)d_out;

    unsigned short* ws16 = (unsigned short*)d_ws;
    unsigned short* Gbf  = ws16;                          // 33,554,432 shorts
    unsigned short* GbfT = Gbf  + (long)B * GSTR;         // 33,554,432
    unsigned short* Wt   = GbfT + (long)B * GSTR;         // 65,536
    unsigned short* NeT  = Wt   + 65536;                  // 4,194,304
    unsigned short* M1sT = NeT  + 4194304;                // 4,194,304
    unsigned short* M2sT = M1sT + 4194304;                // 4,194,304
    float* inv_rs = (float*)(M2sT + 4194304);             // 16384
    float* rs_raw = inv_rs + 16384;
    float* inv_cs = rs_raw + 16384;
    float* prs    = inv_cs + 16384;                       // 8*16*2048
    float* pcs    = prs + (long)B * 16 * NN;              // 8*16*2048
    // total ~162 MB (ws = 512 MiB per harness fill WRITE_SIZE)

    cvt_g<<<dim3(16, 16, 8), 256, 0, stream>>>(G, Gbf, GbfT, prs, pcs);
    finalize<<<dim3(64, 3), 256, 0, stream>>>(prs, pcs, inv_rs, rs_raw, inv_cs, W, Wt);

    const long sNT = 256L * NN;
    // NeT = (H@W)^T : A=H fp32 [b][2048][256]  (TM=64, proven F32ROW staging)
    mgemm<EPI_NE, A_F32ROW, 64><<<dim3(32, 4, 8), 256, 0, stream>>>(
        H, Wt, nullptr, nullptr, NeT, nullptr, nullptr,
        256, 256, 2048L * 256, 0);
    // M1sT = (G@Ne * inv_rs)^T   (TM=128 DMA)
    mgemm<EPI_M1, A_DMA, 128><<<dim3(16, 4, 8), 256, 0, stream>>>(
        Gbf, NeT, nullptr, nullptr, M1sT, nullptr, inv_rs,
        2048, 2048, GSTR, sNT);
    // P2: A=GbfT, B=[NeT ; M1sT] -> M2sT(scaled inv_cs) + out1 + out2
    mgemm<EPI_P2, A_DMA, 128><<<dim3(16, 8, 8), 256, 0, stream>>>(
        GbfT, NeT, M1sT, rs_raw, M2sT, out, inv_cs,
        2048, 2048, GSTR, sNT);
    // out3 = relu(G @ M2s)
    mgemm<EPI_O3, A_DMA, 128><<<dim3(16, 4, 8), 256, 0, stream>>>(
        Gbf, M2sT, nullptr, nullptr, nullptr, out, nullptr,
        2048, 2048, GSTR, sNT);
}

// Round 9
// 373.119 us; speedup vs baseline: 3.3955x; 1.0276x over previous
//
#include <hip/hip_runtime.h>
#include <hip/hip_bf16.h>

// B=8, N=2048, DIN=256, DOUT=256
// Ne = H@W ; M1 = G@Ne ; M2 = G^T@Ne
// out[:,0:256]   = relu(0.5*(M1+M2))
// out[:,256:512] = relu(G^T @ (M1 * inv_rs))
// out[:,512:768] = relu(G   @ (M2 * inv_cs))

constexpr int NN = 2048;
constexpr long GSTR = (long)NN * NN;

using frag8   = __attribute__((ext_vector_type(8))) short;   // 8 bf16
using floatx4 = __attribute__((ext_vector_type(4))) float;
using ush8    = __attribute__((ext_vector_type(8))) unsigned short;

__device__ inline unsigned short f2bf(float x) {
    unsigned u = __float_as_uint(x);
    u += 0x7FFF + ((u >> 16) & 1);   // RNE
    return (unsigned short)(u >> 16);
}
__device__ inline float bf2f(unsigned short h) {
    return __uint_as_float((unsigned)h << 16);
}
__device__ inline ushort2 pk2(float a, float b) {
    union { __hip_bfloat162 h; ushort2 u; } cv;
    cv.h = __float22bfloat162_rn(float2{a, b});
    return cv.u;
}
__device__ inline void gload_lds16(const void* g, void* l) {
    __builtin_amdgcn_global_load_lds(
        (const __attribute__((address_space(1))) void*)g,
        (__attribute__((address_space(3))) void*)l, 16, 0, 0);
}

enum { EPI_NE = 0, EPI_M1 = 1, EPI_P2 = 2, EPI_O3 = 3 };
enum { A_F32ROW = 0, A_DMA = 1 };

// C[i,j] = sum_k Alog[i,k] * Bt[j,k]; Bt bf16 [n][K] staged via global_load_lds.
// LDS (As/Bs): row stride 64 shorts; 16B chunk c of row r at slot c^(r&7)
//   -> fragment ds_read_b128 2-way (free), staging fully coalesced (R6: 0 conflicts).
// Tile TM x 64, BK=64, 4 waves in 2x2 (wave = TM/2 rows x 32 cols).
// 1D grid, XCD-aware decode: xcd = bx&7 owns i-tiles {xcd, xcd+8, ...}; within an
// XCD the NJ j-tiles sharing an A-tile are temporally adjacent -> A-tile hits L2.
template <int EPI, int AMODE, int TM, int NJ>
__global__ __launch_bounds__(256) void mgemm(
    const void* __restrict__ Aptr,
    const unsigned short* __restrict__ B0,
    const unsigned short* __restrict__ B1,     // P2: M1sT (j0>=256 B-source + out1 reconstruct)
    const float* __restrict__ rsraw,           // P2: raw row sums (un-scale M1sT)
    unsigned short* __restrict__ CsT,          // transposed bf16 out [256][2048]
    float* __restrict__ outp,                  // fp32 out base (stride 768)
    const float* __restrict__ scale,           // M1: inv_rs ; P2: inv_cs
    int K, int lda, long strideA, long sB)
{
    constexpr int MF = TM / 32;                // m-frags per wave
    __shared__ __align__(16) unsigned short As[TM * 64];
    __shared__ __align__(16) unsigned short Bs[64 * 64];

    const int t  = threadIdx.x;
    const int bx = blockIdx.x;
    const int xcd = bx & 7;
    const int kk  = bx >> 3;
    constexpr int PER = NJ * 8;                // (j,b) combos per i-tile-group
    const int itile = xcd + 8 * (kk / PER);    // PER is pow2 -> shift
    const int rem   = kk & (PER - 1);
    const int bb    = rem / NJ;                // NJ pow2 -> shift
    const int jt    = rem & (NJ - 1);
    const int i0b = itile * TM;                // batch-local row tile
    const int j0  = jt * 64;

    const unsigned short* Btb =
        ((EPI == EPI_P2 && j0 >= 256) ? B1 + (long)(j0 - 256) * K
                                      : B0 + (long)j0 * K) + (long)bb * sB;

    const int w = t >> 6, l = t & 63;
    const int wm = w >> 1, wn = w & 1;
    const int quad = l >> 4, c15 = l & 15;

    const int lr  = l >> 3, ls = l & 7;  // DMA: row-in-8, slot

    floatx4 acc[MF][2] = {};

    for (int k0 = 0; k0 < K; k0 += 64) {
        // ---- stage A
        if constexpr (AMODE == A_DMA) {
            const unsigned short* Au = (const unsigned short*)Aptr + (long)bb * strideA;
            #pragma unroll
            for (int q = 0; q < TM / 32; ++q) {
                const int rt = q * 32 + w * 8;
                gload_lds16(Au + (long)(i0b + rt + lr) * lda + k0 + ((ls ^ lr) << 3),
                            &As[rt * 64]);
            }
        } else {  // A_F32ROW (NE over fp32 H), TM=64: 16 floats/thread
            const float* Af = (const float*)Aptr + (long)bb * strideA;
            const int ar  = t >> 2;
            const int ac0 = (t & 3) * 2;
            const float* ap = Af + (long)(i0b + ar) * lda + k0 + ac0 * 8;
            const float4 x0 = *(const float4*)(ap + 0);
            const float4 x1 = *(const float4*)(ap + 4);
            const float4 x2 = *(const float4*)(ap + 8);
            const float4 x3 = *(const float4*)(ap + 12);
            union { ush8 v; ushort2 u2[4]; } p0, p1;
            p0.u2[0] = pk2(x0.x, x0.y); p0.u2[1] = pk2(x0.z, x0.w);
            p0.u2[2] = pk2(x1.x, x1.y); p0.u2[3] = pk2(x1.z, x1.w);
            p1.u2[0] = pk2(x2.x, x2.y); p1.u2[1] = pk2(x2.z, x2.w);
            p1.u2[2] = pk2(x3.x, x3.y); p1.u2[3] = pk2(x3.z, x3.w);
            const int sw = ar & 7;
            *(ush8*)&As[ar * 64 + ((ac0 ^ sw) << 3)]       = p0.v;
            *(ush8*)&As[ar * 64 + (((ac0 + 1) ^ sw) << 3)] = p1.v;
        }
        // ---- stage B (always DMA)
        #pragma unroll
        for (int q = 0; q < 2; ++q) {
            const int rt = w * 16 + q * 8;
            gload_lds16(Btb + (long)(rt + lr) * K + k0 + ((ls ^ lr) << 3),
                        &Bs[rt * 64]);
        }
        __syncthreads();

        #pragma unroll
        for (int ks = 0; ks < 2; ++ks) {
            frag8 af[MF], bfv[2];
            const int swr = c15 & 7;
            #pragma unroll
            for (int mt = 0; mt < MF; ++mt)
                af[mt] = *(const frag8*)&As[(wm * (TM / 2) + mt * 16 + c15) * 64
                                            + (((ks * 4 + quad) ^ swr) << 3)];
            #pragma unroll
            for (int nt = 0; nt < 2; ++nt)
                bfv[nt] = *(const frag8*)&Bs[(wn * 32 + nt * 16 + c15) * 64
                                             + (((ks * 4 + quad) ^ swr) << 3)];
            #pragma unroll
            for (int mt = 0; mt < MF; ++mt)
                #pragma unroll
                for (int nt = 0; nt < 2; ++nt)
                    acc[mt][nt] = __builtin_amdgcn_mfma_f32_16x16x32_bf16(
                        af[mt], bfv[nt], acc[mt][nt], 0, 0, 0);
        }
        __syncthreads();
    }

    // ---- epilogue: C/D layout col=lane&15, row=quad*4+reg
    const long rowb = (long)bb * NN;
    #pragma unroll
    for (int mt = 0; mt < MF; ++mt) {
        const int il = wm * (TM / 2) + mt * 16 + quad * 4;
        const int ib = i0b + il;
        float4 s4 = make_float4(1.f, 1.f, 1.f, 1.f);
        if constexpr (EPI == EPI_M1) s4 = *(const float4*)(scale + rowb + ib);
        if constexpr (EPI == EPI_P2) {
            if (j0 < 256) s4 = *(const float4*)(scale + rowb + ib);
        }
        #pragma unroll
        for (int nt = 0; nt < 2; ++nt) {
            floatx4 v = acc[mt][nt];
            const int gj = j0 + wn * 32 + nt * 16 + c15;
            if constexpr (EPI == EPI_NE) {
                union { ushort4 v; ushort2 u2[2]; } p;
                p.u2[0] = pk2(v[0], v[1]); p.u2[1] = pk2(v[2], v[3]);
                *(ushort4*)(CsT + ((long)bb * 256 + gj) * 2048 + ib) = p.v;
            } else if constexpr (EPI == EPI_M1) {
                union { ushort4 v; ushort2 u2[2]; } p;
                p.u2[0] = pk2(v[0] * s4.x, v[1] * s4.y);
                p.u2[1] = pk2(v[2] * s4.z, v[3] * s4.w);
                *(ushort4*)(CsT + ((long)bb * 256 + gj) * 2048 + ib) = p.v;
            } else if constexpr (EPI == EPI_P2) {
                if (j0 < 256) {
                    union { ushort4 v; ushort2 u2[2]; } p;
                    p.u2[0] = pk2(v[0] * s4.x, v[1] * s4.y);
                    p.u2[1] = pk2(v[2] * s4.z, v[3] * s4.w);
                    *(ushort4*)(CsT + ((long)bb * 256 + gj) * 2048 + ib) = p.v;
                    // out1: reconstruct M1 = M1sT * rs_raw
                    const float4 rr = *(const float4*)(rsraw + rowb + ib);
                    const ushort4 m1p = *(const ushort4*)(B1 + ((long)bb * 256 + gj) * 2048 + ib);
                    const float m1v[4] = {bf2f(m1p.x) * rr.x, bf2f(m1p.y) * rr.y,
                                          bf2f(m1p.z) * rr.z, bf2f(m1p.w) * rr.w};
                    #pragma unroll
                    for (int r = 0; r < 4; ++r)
                        outp[(rowb + ib + r) * 768 + gj] = fmaxf(0.5f * (v[r] + m1v[r]), 0.f);
                } else {
                    #pragma unroll
                    for (int r = 0; r < 4; ++r)
                        outp[(rowb + ib + r) * 768 + gj] = fmaxf(v[r], 0.f);  // gj in [256,512)
                }
            } else {  // EPI_O3
                #pragma unroll
                for (int r = 0; r < 4; ++r)
                    outp[(rowb + ib + r) * 768 + 512 + gj] = fmaxf(v[r], 0.f);
            }
        }
    }
}

// ---- fused: G fp32 -> Gbf + GbfT + row/col partial sums ----
// 128x128 tile, 256 threads. R9: ALL 16 float4 loads hoisted into registers
// before any compute (R8's VGPR=52 showed the compiler was serializing loads
// into the dependent cvt/shuffle chain -> latency-bound at 2.5 TB/s).
__global__ __launch_bounds__(256) void cvt_g(
    const float* __restrict__ G,
    unsigned short* __restrict__ Gbf, unsigned short* __restrict__ GbfT,
    float* __restrict__ prs, float* __restrict__ pcs)
{
    __shared__ __align__(16) unsigned short Tb[128 * 136];
    __shared__ float cpw[4][128];

    const int b  = blockIdx.z;
    const int j0 = blockIdx.x * 128, i0 = blockIdx.y * 128;
    const int t  = threadIdx.x;
    const int c  = t & 15;        // 8-elem chunk along j (phase A) / i (phase B)
    const int rg = t >> 4;        // 0..15 row group
    const int w  = t >> 6, l16 = (t & 63) >> 4;

    // ---- phase A0: issue all 16 loads (deep in flight)
    float4 xs[16];
    #pragma unroll
    for (int p = 0; p < 8; ++p) {
        const long gb = (long)b * GSTR + (long)(i0 + p * 16 + rg) * NN + j0 + c * 8;
        xs[2 * p]     = *(const float4*)(G + gb);
        xs[2 * p + 1] = *(const float4*)(G + gb + 4);
    }

    float cs[8] = {};
    // ---- phase A1: convert, write Gbf, stage LDS, row sums, col accum
    #pragma unroll
    for (int p = 0; p < 8; ++p) {
        const int row = p * 16 + rg;                 // tile-local i
        const long gb = (long)b * GSTR + (long)(i0 + row) * NN + j0 + c * 8;
        const float4 x0 = xs[2 * p], x1 = xs[2 * p + 1];
        union { ush8 v; ushort2 u2[4]; } pk;
        pk.u2[0] = pk2(x0.x, x0.y); pk.u2[1] = pk2(x0.z, x0.w);
        pk.u2[2] = pk2(x1.x, x1.y); pk.u2[3] = pk2(x1.z, x1.w);
        *(ush8*)(Gbf + gb) = pk.v;
        *(ush8*)&Tb[row * 136 + (((c + (row >> 3)) & 15) << 3)] = pk.v;

        float rp = x0.x + x0.y + x0.z + x0.w + x1.x + x1.y + x1.z + x1.w;
        rp += __shfl_xor(rp, 1);
        rp += __shfl_xor(rp, 2);
        rp += __shfl_xor(rp, 4);
        rp += __shfl_xor(rp, 8);
        if (c == 0) prs[((long)b * 16 + blockIdx.x) * NN + i0 + row] = rp;

        cs[0] += x0.x; cs[1] += x0.y; cs[2] += x0.z; cs[3] += x0.w;
        cs[4] += x1.x; cs[5] += x1.y; cs[6] += x1.z; cs[7] += x1.w;
    }

    // col partials: reduce across the wave's 4 row-groups, then cross-wave via LDS
    #pragma unroll
    for (int e = 0; e < 8; ++e) {
        cs[e] += __shfl_xor(cs[e], 16);
        cs[e] += __shfl_xor(cs[e], 32);
    }
    if (l16 == 0) {
        #pragma unroll
        for (int e = 0; e < 8; ++e) cpw[w][c * 8 + e] = cs[e];
    }
    __syncthreads();
    if (t < 128)
        pcs[((long)b * 16 + blockIdx.y) * NN + j0 + t] =
            cpw[0][t] + cpw[1][t] + cpw[2][t] + cpw[3][t];

    // ---- phase B: GbfT[j][i] from LDS (scalar column reads, 256-B stores)
    #pragma unroll
    for (int q = 0; q < 8; ++q) {
        const int jr = q * 16 + rg;                  // tile-local j
        union { ush8 v; unsigned short a[8]; } pk;
        #pragma unroll
        for (int r = 0; r < 8; ++r) {
            const int i = c * 8 + r;
            pk.a[r] = Tb[i * 136 + ((((jr >> 3) + c) & 15) << 3) + (jr & 7)];
        }
        *(ush8*)(GbfT + (long)b * GSTR + (long)(j0 + jr) * NN + i0 + c * 8) = pk.v;
    }
}

// reduce partials + W transpose: y=0 -> inv_rs+rs_raw ; y=1 -> inv_cs ; y=2 -> Wt
__global__ __launch_bounds__(256) void finalize(
    const float* __restrict__ prs, const float* __restrict__ pcs,
    float* __restrict__ inv_rs, float* __restrict__ rs_raw,
    float* __restrict__ inv_cs,
    const float* __restrict__ W, unsigned short* __restrict__ Wt)
{
    const int idx = blockIdx.x * 256 + threadIdx.x;   // 0..16383
    if (blockIdx.y == 0) {
        const int b = idx >> 11, i = idx & 2047;
        float s = 0.f;
        #pragma unroll
        for (int jc = 0; jc < 16; ++jc) s += prs[((long)b * 16 + jc) * NN + i];
        inv_rs[idx] = 1.0f / s;
        rs_raw[idx] = s;
    } else if (blockIdx.y == 1) {
        const int b = idx >> 11, i = idx & 2047;
        float s = 0.f;
        #pragma unroll
        for (int ic = 0; ic < 16; ++ic) s += pcs[((long)b * 16 + ic) * NN + i];
        inv_cs[idx] = 1.0f / s;
    } else {
        #pragma unroll
        for (int e = 0; e < 4; ++e) {
            const int flat = idx * 4 + e;              // 0..65535
            const int j = flat >> 8, k = flat & 255;
            Wt[flat] = f2bf(W[(long)k * 256 + j]);
        }
    }
}

extern "C" void kernel_launch(void* const* d_in, const int* in_sizes, int n_in,
                              void* d_out, int out_size, void* d_ws, size_t ws_size,
                              hipStream_t stream)
{
    constexpr int B = 8;
    const float* H = (const float*)d_in[0];
    const float* G = (const float*)d_in[1];
    const float* W = (const float*)d_in[2];
    float* out = (float*)d_out;

    unsigned short* ws16 = (unsigned short*)d_ws;
    unsigned short* Gbf  = ws16;                          // 33,554,432 shorts
    unsigned short* GbfT = Gbf  + (long)B * GSTR;         // 33,554,432
    unsigned short* Wt   = GbfT + (long)B * GSTR;         // 65,536
    unsigned short* NeT  = Wt   + 65536;                  // 4,194,304
    unsigned short* M1sT = NeT  + 4194304;                // 4,194,304
    unsigned short* M2sT = M1sT + 4194304;                // 4,194,304
    float* inv_rs = (float*)(M2sT + 4194304);             // 16384
    float* rs_raw = inv_rs + 16384;
    float* inv_cs = rs_raw + 16384;
    float* prs    = inv_cs + 16384;                       // 8*16*2048
    float* pcs    = prs + (long)B * 16 * NN;              // 8*16*2048
    // total ~162 MB (ws = 512 MiB per harness fill WRITE_SIZE)

    cvt_g<<<dim3(16, 16, 8), 256, 0, stream>>>(G, Gbf, GbfT, prs, pcs);
    finalize<<<dim3(64, 3), 256, 0, stream>>>(prs, pcs, inv_rs, rs_raw, inv_cs, W, Wt);

    const long sNT = 256L * NN;
    // NeT = (H@W)^T : A=H fp32 [b][2048][256]  (TM=64, 32 i-tiles x 4 j x 8 b)
    mgemm<EPI_NE, A_F32ROW, 64, 4><<<1024, 256, 0, stream>>>(
        H, Wt, nullptr, nullptr, NeT, nullptr, nullptr,
        256, 256, 2048L * 256, 0);
    // M1sT = (G@Ne * inv_rs)^T   (TM=128: 16 i-tiles x 4 j x 8 b)
    mgemm<EPI_M1, A_DMA, 128, 4><<<512, 256, 0, stream>>>(
        Gbf, NeT, nullptr, nullptr, M1sT, nullptr, inv_rs,
        2048, 2048, GSTR, sNT);
    // P2: A=GbfT, B=[NeT ; M1sT] -> M2sT(scaled inv_cs) + out1 + out2 (8 j-tiles)
    mgemm<EPI_P2, A_DMA, 128, 8><<<1024, 256, 0, stream>>>(
        GbfT, NeT, M1sT, rs_raw, M2sT, out, inv_cs,
        2048, 2048, GSTR, sNT);
    // out3 = relu(G @ M2s)
    mgemm<EPI_O3, A_DMA, 128, 4><<<512, 256, 0, stream>>>(
        Gbf, M2sT, nullptr, nullptr, nullptr, out, nullptr,
        2048, 2048, GSTR, sNT);
}